// Round 5
// baseline (386.328 us; speedup 1.0000x reference)
//
#include <hip/hip_runtime.h>
#include <hip/hip_bf16.h>

// Problem constants (from reference)
#define NN      50000
#define EE      200000
#define IN_DIM  32
#define HID     64
#define HEADS   4
#define OUTD    32
#define TSTEPS  3

typedef unsigned short bf16_t;
typedef __attribute__((ext_vector_type(8))) short  short8;
typedef __attribute__((ext_vector_type(4))) float  floatx4;

__device__ __forceinline__ float b2f(bf16_t u) {
    union { unsigned int i; float f; } v; v.i = ((unsigned int)u) << 16; return v.f;
}
__device__ __forceinline__ bf16_t f2b(float f) {
    union { float f; unsigned int i; } v; v.f = f;
    unsigned int r = v.i + 0x7FFF + ((v.i >> 16) & 1);   // RNE
    return (bf16_t)(r >> 16);
}

// DPP-based add of a lane-permuted copy (all lanes valid, bound_ctrl=1).
// 0xB1=quad_perm[1,0,3,2](xor1), 0x4E=quad_perm[2,3,0,1](xor2),
// 0x141=row_half_mirror, 0x140=row_mirror. Chain of 4 = sum over each 16-lane group.
#define DPP_ADD(x, ctrl) ((x) + __int_as_float(                                 \
        __builtin_amdgcn_update_dpp(0, __float_as_int(x), (ctrl), 0xF, 0xF, true)))

#define H0_BLOCKS ((NN + 63) / 64)   // h0 section: 64 nodes/block
#define NB_NODE   ((NN + 255) / 256) // 196 blocks covering node range
#define EB        ((EE + 1023) / 1024) // edge-hist blocks (4 edges/thread)

// ---------------------------------------------------------------- fused setup (+h0 +edge hist)
__global__ __launch_bounds__(256) void k_setup(
        const void* W_in, const void* b_in, const void* att, const void* bconv,
        const void* Wg, const void* bg,
        const void* Wl_raw, const void* Wr_raw, const void* bl_raw, const void* br_raw,
        const void* feat_raw, const int* __restrict__ nmask,
        const int* __restrict__ e_src, const int* __restrict__ e_dst,
        float* attf, float* bcf, float* Wgf, float* bgf,
        bf16_t* __restrict__ Wt, bf16_t* __restrict__ WtS, float* __restrict__ bb,
        int* __restrict__ deg4, int* __restrict__ flag,
        bf16_t* __restrict__ h0, bf16_t* __restrict__ h) {
    __shared__ int bad;
    __shared__ float Ws[IN_DIM * HID];
    __shared__ float bs[HID];
    int t = threadIdx.x, bid = blockIdx.x;
    if (t == 0) bad = 0;
    __syncthreads();
    {
        const bf16_t* p = (const bf16_t*)W_in;
        int mybad = 0;
        for (int i = t; i < IN_DIM * HID; i += 256) {
            float v = b2f(p[i]);
            if (v != v || fabsf(v) > 100.f) mybad = 1;
        }
        if (mybad) atomicOr(&bad, 1);
    }
    __syncthreads();
    int f = bad ? 0 : 1;
    if (bid == 0 && t == 0) *flag = f;

    if (bid < 256) {
        int i = bid * 256 + t;              // over 512*128
        int n = i >> 7, k = i & 127;
        const void* W = (n < 256) ? Wl_raw : Wr_raw;
        int nn = (n < 256) ? n : n - 256;
        float v = f ? b2f(((const bf16_t*)W)[k * 256 + nn])
                    : ((const float*)W)[k * 256 + nn];
        Wt[n * 128 + k] = f2b(v);
        if (k < 64) {
            float v2 = f ? b2f(((const bf16_t*)W)[(k + 64) * 256 + nn])
                         : ((const float*)W)[(k + 64) * 256 + nn];
            WtS[n * 64 + k] = f2b(v + v2);   // step-0 weights: x=[h0|h0]
        }
        if (k == 0) {
            const void* b = (n < 256) ? bl_raw : br_raw;
            bb[n] = f ? b2f(((const bf16_t*)b)[nn]) : ((const float*)b)[nn];
        }
    } else if (bid < 267) {
        int i = (bid - 256) * 256 + t;      // over 2592
        const void* src; float* dst; int off;
        if      (i < 256)  { src = att;   dst = attf; off = i; }
        else if (i < 512)  { src = bconv; dst = bcf;  off = i - 256; }
        else if (i < 2560) { src = Wg;    dst = Wgf;  off = i - 512; }
        else if (i < 2592) { src = bg;    dst = bgf;  off = i - 2560; }
        else return;
        dst[off] = f ? b2f(((const bf16_t*)src)[off]) : ((const float*)src)[off];
    } else if (bid < 267 + EB) {
        // edge histogram: per-(dst, src-mask-bucket) degree (deg4 zeroed by host memset)
        int nb = bid - 267;
        int i = (nb * 256 + t) * 4;
        if (i + 3 < EE) {
            int4 dv = *(const int4*)(e_dst + i);
            int4 sv = *(const int4*)(e_src + i);
            int m0 = nmask[sv.x]; m0 = m0 < 0 ? 0 : (m0 > 3 ? 3 : m0);
            int m1 = nmask[sv.y]; m1 = m1 < 0 ? 0 : (m1 > 3 ? 3 : m1);
            int m2 = nmask[sv.z]; m2 = m2 < 0 ? 0 : (m2 > 3 ? 3 : m2);
            int m3 = nmask[sv.w]; m3 = m3 < 0 ? 0 : (m3 > 3 ? 3 : m3);
            atomicAdd(&deg4[dv.x * 4 + m0], 1);
            atomicAdd(&deg4[dv.y * 4 + m1], 1);
            atomicAdd(&deg4[dv.z * 4 + m2], 1);
            atomicAdd(&deg4[dv.w * 4 + m3], 1);
        } else {
            for (; i < EE; i++) {
                int s = e_src[i];
                int m = nmask[s]; m = m < 0 ? 0 : (m > 3 ? 3 : m);
                atomicAdd(&deg4[e_dst[i] * 4 + m], 1);
            }
        }
    } else {
        // h0: stage W_in/b_in once, then 16 groups x 4 nodes = 64 nodes/block
        for (int i = t; i < IN_DIM * HID; i += 256)
            Ws[i] = f ? b2f(((const bf16_t*)W_in)[i]) : ((const float*)W_in)[i];
        if (t < HID)
            bs[t] = f ? b2f(((const bf16_t*)b_in)[t]) : ((const float*)b_in)[t];
        __syncthreads();
        int nb = bid - (267 + EB);
        int wid = t >> 6, c = t & 63;
#pragma unroll
        for (int g = 0; g < 16; g++) {
            int node = (nb * 16 + g) * 4 + wid;
            if (node >= NN) break;
            float acc = bs[c];
            if (f) {
                const short8* fr8 = (const short8*)((const bf16_t*)feat_raw
                                                    + (size_t)node * IN_DIM);
#pragma unroll
                for (int j = 0; j < 4; j++) {
                    short8 fv = fr8[j];
#pragma unroll
                    for (int k = 0; k < 8; k++)
                        acc += b2f((bf16_t)fv[k]) * Ws[(j * 8 + k) * HID + c];
                }
            } else {
                const float4* fr4 = (const float4*)((const float*)feat_raw
                                                    + (size_t)node * IN_DIM);
#pragma unroll
                for (int j = 0; j < 8; j++) {
                    float4 fv = fr4[j];
                    acc += fv.x * Ws[(j * 4 + 0) * HID + c];
                    acc += fv.y * Ws[(j * 4 + 1) * HID + c];
                    acc += fv.z * Ws[(j * 4 + 2) * HID + c];
                    acc += fv.w * Ws[(j * 4 + 3) * HID + c];
                }
            }
            bf16_t o = f2b(acc);
            h0[(size_t)node * HID + c] = o;
            h [(size_t)node * HID + c] = o;
        }
    }
}

// ---------------------------------------------------------------- single-kernel scan over deg4
// Builds per-node bucket cursors cur4 and rend4 = {end0,end1,end2,row_start}.
// Also builds the 64-class histogram (mask-bucket desc x live-degree class)
// used to make order[] degree-stratified for k_agg load balance.
__global__ __launch_bounds__(256) void k_scan(const int* __restrict__ deg4,
                                              const int* __restrict__ nmask,
                                              int* __restrict__ cur4,
                                              int* __restrict__ rend4,
                                              int* __restrict__ clscnt,
                                              int n) {
    __shared__ int sc[256];
    __shared__ int spre[256];
    __shared__ int lhist[64];
    int t = threadIdx.x, bid = blockIdx.x;
    if (t < 64) lhist[t] = 0;

    const int4* d4 = (const int4*)deg4;   // one int4 = one node's 4 bucket degrees
    int base = bid * 1024;
    // global prefix of all nodes before this chunk
    int pre = 0;
    for (int i = t; i < base; i += 256) {
        int4 q = d4[i];
        pre += q.x + q.y + q.z + q.w;
    }
    spre[t] = pre; __syncthreads();
    for (int off = 128; off > 0; off >>= 1) {
        if (t < off) spre[t] += spre[t + off];
        __syncthreads();
    }
    int bpref = spre[0];

    int4 dd[4]; int tot[4]; int s = 0;
#pragma unroll
    for (int j = 0; j < 4; j++) {
        int i = base + t * 4 + j;
        if (i < n) dd[j] = d4[i];
        else { dd[j].x = 0; dd[j].y = 0; dd[j].z = 0; dd[j].w = 0; }
        tot[j] = dd[j].x + dd[j].y + dd[j].z + dd[j].w;
        s += tot[j];
    }
    sc[t] = s; __syncthreads();
    for (int off = 1; off < 256; off <<= 1) {
        int add = (t >= off) ? sc[t - off] : 0;
        __syncthreads();
        sc[t] += add;
        __syncthreads();
    }
    int run = sc[t] - s + bpref;
#pragma unroll
    for (int j = 0; j < 4; j++) {
        int i = base + t * 4 + j;
        if (i < n) {
            int c3 = run;                 // start of bucket 3
            int c2 = c3 + dd[j].w;        // start of bucket 2
            int c1 = c2 + dd[j].z;        // start of bucket 1
            int c0 = c1 + dd[j].y;        // start of bucket 0
            int4 cu; cu.x = c0; cu.y = c1; cu.z = c2; cu.w = c3;
            *(int4*)(cur4 + i * 4) = cu;
            int4 re; re.x = c0; re.y = c1; re.z = c2; re.w = run;  // ends + row start
            *(int4*)(rend4 + i * 4) = re;
            // class: (3-mask_bucket)*16 + min(live_step0_degree, 15)
            int m = nmask[i]; m = m < 0 ? 0 : (m > 3 ? 3 : m);
            int d = dd[j].y + dd[j].z + dd[j].w;
            int dc = d > 15 ? 15 : d;
            atomicAdd(&lhist[(3 - m) * 16 + dc], 1);
        }
        run += tot[j];
    }
    __syncthreads();
    if (t < 64 && lhist[t]) atomicAdd(&clscnt[t], lhist[t]);
}

// ---------------------------------------------------------------- scatter: bucket-sorted CSR cols + degree-stratified order
__global__ __launch_bounds__(256) void k_scatter_all(const int* __restrict__ src,
                                                     const int* __restrict__ dst,
                                                     int* __restrict__ cur4,
                                                     int* __restrict__ col,
                                                     const int* __restrict__ mask,
                                                     const int* __restrict__ rend4,
                                                     const int* __restrict__ clscnt,
                                                     int* __restrict__ clscur,
                                                     int* __restrict__ mbuf,
                                                     int* __restrict__ order) {
    int t = threadIdx.x, bid = blockIdx.x;
    int i = bid * 256 + t;
    if (i < EE) {
        int sv = src[i];
        int m = mask[sv]; m = m < 0 ? 0 : (m > 3 ? 3 : m);
        int d = dst[i];
        int pos = atomicAdd(&cur4[d * 4 + m], 1);
        col[pos] = sv;                       // bucket-sorted: no mask packing needed
    }
    if (bid < NB_NODE) {
        __shared__ int sbase[64];
        if (t == 0) {                        // tiny redundant per-block prefix (64 ints)
            int a = 0;
            for (int c = 0; c < 64; c++) { sbase[c] = a; a += clscnt[c]; }
        }
        __syncthreads();
        if (bid == 0 && t == 0) {
            mbuf[8]  = sbase[48];            // active at step 0 (classes 0..47 = mask>=1)
            mbuf[9]  = sbase[32];            // step 1 (mask>=2)
            mbuf[10] = sbase[16];            // step 2 (mask==3)
        }
        int ni = bid * 256 + t;
        if (ni < NN) {
            int m = mask[ni]; m = m < 0 ? 0 : (m > 3 ? 3 : m);
            int4 re = *(const int4*)(rend4 + ni * 4);
            int d = re.x - re.w;             // live step-0 degree
            int dc = d > 15 ? 15 : d;
            int cls = (3 - m) * 16 + dc;
            int pos = sbase[cls] + atomicAdd(&clscur[cls], 1);
            order[pos] = ni;                 // sorted by mask desc, then degree asc
        }
    }
}

// ---------------------------------------------------------------- step-0 MFMA GEMM (K=64, pre-summed weights)
__global__ __launch_bounds__(256) void k_gemm0(const bf16_t* __restrict__ h0,
                                               const bf16_t* __restrict__ WtS,
                                               const float* __restrict__ bb,
                                               bf16_t* __restrict__ xl,
                                               bf16_t* __restrict__ xr,
                                               const int* __restrict__ order,
                                               const int* __restrict__ mbuf) {
    int count = mbuf[8];
    int mbase = blockIdx.x * 64;
    if (mbase >= count) return;

    __shared__ bf16_t smem[64 * 72 + 128 * 72];   // 27.6 KB
    bf16_t* As = smem;
    bf16_t* Bs = smem + 64 * 72;
    bf16_t* Cs = smem;                             // 64*136=8704 <= 13824

    int t = threadIdx.x;
    int nbase = blockIdx.y * 128;

    {
        int ln = t >> 2, lq = t & 3;
        int idx = mbase + ln;
        int node = (idx < count) ? order[idx] : -1;
        ulonglong2 z; z.x = 0; z.y = 0;
        ulonglong2 v0 = z, v1 = z;
        if (node >= 0) {
            v0 = *(const ulonglong2*)(h0 + (size_t)node * HID + lq * 16);
            v1 = *(const ulonglong2*)(h0 + (size_t)node * HID + lq * 16 + 8);
        }
        *(ulonglong2*)(&As[ln * 72 + lq * 16]) = v0;
        *(ulonglong2*)(&As[ln * 72 + lq * 16 + 8]) = v1;
    }
    {
        int n = t >> 1, kc = (t & 1) * 32;
        const bf16_t* srcp = WtS + (size_t)(nbase + n) * 64 + kc;
        bf16_t* dstp = &Bs[n * 72 + kc];
        *(ulonglong2*)(dstp)      = *(const ulonglong2*)(srcp);
        *(ulonglong2*)(dstp + 8)  = *(const ulonglong2*)(srcp + 8);
        *(ulonglong2*)(dstp + 16) = *(const ulonglong2*)(srcp + 16);
        *(ulonglong2*)(dstp + 24) = *(const ulonglong2*)(srcp + 24);
    }
    __syncthreads();

    int wv = t >> 6, lane = t & 63, mrow = lane & 15, quad = lane >> 4;
    floatx4 acc[8];
#pragma unroll
    for (int nf = 0; nf < 8; nf++) acc[nf] = (floatx4){0.f, 0.f, 0.f, 0.f};
#pragma unroll
    for (int kq = 0; kq < 2; kq++) {
        short8 a = *(const short8*)(&As[(wv * 16 + mrow) * 72 + kq * 32 + quad * 8]);
#pragma unroll
        for (int nf = 0; nf < 8; nf++) {
            short8 b = *(const short8*)(&Bs[(nf * 16 + mrow) * 72 + kq * 32 + quad * 8]);
            acc[nf] = __builtin_amdgcn_mfma_f32_16x16x32_bf16(a, b, acc[nf], 0, 0, 0);
        }
    }
    __syncthreads();

#pragma unroll
    for (int nf = 0; nf < 8; nf++) {
        float bv = bb[nbase + nf * 16 + mrow];
#pragma unroll
        for (int r = 0; r < 4; r++) {
            int m = wv * 16 + quad * 4 + r;
            Cs[m * 136 + nf * 16 + mrow] = f2b(acc[nf][r] + bv);
        }
    }
    __syncthreads();

    bf16_t* outp = (blockIdx.y < 2) ? xl : xr;
    int cc = (blockIdx.y & 1) * 128;
#pragma unroll
    for (int i = 0; i < 4; i++) {
        int c = t + i * 256;
        int m = c >> 4, kc = (c & 15) * 8;
        int idx = mbase + m;
        if (idx < count) {
            int node = order[idx];
            *(ulonglong2*)(outp + (size_t)node * 256 + cc + kc) =
                *(const ulonglong2*)(&Cs[m * 136 + kc]);
        }
    }
}

// ---------------------------------------------------------------- steps 1-2 MFMA GEMM (K=128)
__global__ __launch_bounds__(256) void k_gemm_mfma(const bf16_t* __restrict__ h,
                                                   const bf16_t* __restrict__ h0,
                                                   const bf16_t* __restrict__ Wt,
                                                   const float* __restrict__ bb,
                                                   bf16_t* __restrict__ xl,
                                                   bf16_t* __restrict__ xr,
                                                   const int* __restrict__ order,
                                                   const int* __restrict__ mbuf,
                                                   int step) {
    int count = mbuf[8 + step];
    int mbase = blockIdx.x * 64;
    if (mbase >= count) return;

    __shared__ bf16_t smem[64 * 136 + 128 * 136];   // 52 KB
    bf16_t* As = smem;
    bf16_t* Bs = smem + 64 * 136;
    bf16_t* Cs = smem;

    int t = threadIdx.x;
    int nbase = blockIdx.y * 128;

    {
        int ln = t >> 2, lq = t & 3;
        int idx = mbase + ln;
        int node = (idx < count) ? order[idx] : -1;
        ulonglong2 z; z.x = 0; z.y = 0;
#pragma unroll
        for (int j = 0; j < 2; j++) {
            int chunk = lq + j * 4;
            ulonglong2 vh = z, vh0 = z;
            if (node >= 0) {
                vh  = *(const ulonglong2*)(h  + (size_t)node * HID + chunk * 8);
                vh0 = *(const ulonglong2*)(h0 + (size_t)node * HID + chunk * 8);
            }
            *(ulonglong2*)(&As[ln * 136 + chunk * 8]) = vh;
            *(ulonglong2*)(&As[ln * 136 + 64 + chunk * 8]) = vh0;
        }
    }
#pragma unroll
    for (int i = 0; i < 8; i++) {
        int c = t + i * 256;
        int n = c >> 4, kc = (c & 15) * 8;
        *(ulonglong2*)(&Bs[n * 136 + kc]) =
            *(const ulonglong2*)(Wt + (size_t)(nbase + n) * 128 + kc);
    }
    __syncthreads();

    int wv = t >> 6, lane = t & 63, mrow = lane & 15, quad = lane >> 4;
    floatx4 acc[8];
#pragma unroll
    for (int nf = 0; nf < 8; nf++) acc[nf] = (floatx4){0.f, 0.f, 0.f, 0.f};
#pragma unroll
    for (int kq = 0; kq < 4; kq++) {
        short8 a = *(const short8*)(&As[(wv * 16 + mrow) * 136 + kq * 32 + quad * 8]);
#pragma unroll
        for (int nf = 0; nf < 8; nf++) {
            short8 b = *(const short8*)(&Bs[(nf * 16 + mrow) * 136 + kq * 32 + quad * 8]);
            acc[nf] = __builtin_amdgcn_mfma_f32_16x16x32_bf16(a, b, acc[nf], 0, 0, 0);
        }
    }
    __syncthreads();

#pragma unroll
    for (int nf = 0; nf < 8; nf++) {
        float bv = bb[nbase + nf * 16 + mrow];
#pragma unroll
        for (int r = 0; r < 4; r++) {
            int m = wv * 16 + quad * 4 + r;
            Cs[m * 136 + nf * 16 + mrow] = f2b(acc[nf][r] + bv);
        }
    }
    __syncthreads();

    bf16_t* outp = (blockIdx.y < 2) ? xl : xr;
    int cc = (blockIdx.y & 1) * 128;
#pragma unroll
    for (int i = 0; i < 4; i++) {
        int c = t + i * 256;
        int m = c >> 4, kc = (c & 15) * 8;
        int idx = mbase + m;
        if (idx < count) {
            int node = order[idx];
            *(ulonglong2*)(outp + (size_t)node * 256 + cc + kc) =
                *(const ulonglong2*)(&Cs[m * 136 + kc]);
        }
    }
}

// ---------------------------------------------------------------- segment softmax + aggregate (in-place bf16 h)
// order[] is degree-stratified: grid-stride sampling gives every wave a nearly
// identical work profile -> no straggler tail (R1 showed Occupancy 32% = tail-bound).
__global__ __launch_bounds__(256) void k_agg(bf16_t* __restrict__ h,
                                             const bf16_t* __restrict__ xl,
                                             const bf16_t* __restrict__ xr,
                                             const float* __restrict__ att,
                                             const float* __restrict__ b_conv,
                                             const int* __restrict__ rend4,
                                             const int* __restrict__ col,
                                             const int* __restrict__ order,
                                             const int* __restrict__ mbuf,
                                             int step) {
    int count = mbuf[8 + step];
    int wid = threadIdx.x >> 6;
    int lane = threadIdx.x & 63;
    const int stride = gridDim.x * 4;
    float4 attv = *(const float4*)(att + lane * 4);
    // prescale by log2(e): exp(score) == exp2(score_scaled), saves a dependent mul
    attv.x *= 1.44269504f; attv.y *= 1.44269504f;
    attv.z *= 1.44269504f; attv.w *= 1.44269504f;
    float4 bcv  = *(const float4*)(b_conv + lane * 4);

    int idx = blockIdx.x * 4 + wid;
    if (idx >= count) return;

    int node = order[idx];
    int4 re = *(const int4*)(rend4 + node * 4);
    ushort4 xru   = *(const ushort4*)(xr + (size_t)node * 256 + lane * 4);
    ushort4 uself = *(const ushort4*)(xl + (size_t)node * 256 + lane * 4);

    for (;;) {
        // ---- issue next node's full preamble NOW (hidden under current compute)
        int nidx = idx + stride;
        bool more = nidx < count;
        int nnode = order[more ? nidx : idx];
        int4 re_n = *(const int4*)(rend4 + nnode * 4);
        ushort4 xru_n   = *(const ushort4*)(xr + (size_t)nnode * 256 + lane * 4);
        ushort4 uself_n = *(const ushort4*)(xl + (size_t)nnode * 256 + lane * 4);

        // ---- process current node
        int e0 = re.w;
        int e1 = (step == 0) ? re.x : (step == 1) ? re.y : re.z;

        float xr0 = b2f(xru.x), xr1 = b2f(xru.y), xr2 = b2f(xru.z), xr3 = b2f(xru.w);
        float a0 = 0.f, a1 = 0.f, a2 = 0.f, a3 = 0.f, l = 0.f;

        auto ld = [&](int s) {
            return *(const ushort4*)(xl + (size_t)s * 256 + lane * 4);
        };
        auto body = [&](ushort4 xu) {
            float x0 = b2f(xu.x), x1 = b2f(xu.y), x2 = b2f(xu.z), x3 = b2f(xu.w);
            float v0 = x0 + xr0; v0 = fmaxf(v0, 0.2f * v0);
            float v1 = x1 + xr1; v1 = fmaxf(v1, 0.2f * v1);
            float v2 = x2 + xr2; v2 = fmaxf(v2, 0.2f * v2);
            float v3 = x3 + xr3; v3 = fmaxf(v3, 0.2f * v3);
            float part = attv.x * v0 + attv.y * v1 + attv.z * v2 + attv.w * v3;
            part = DPP_ADD(part, 0xB1);    // xor1
            part = DPP_ADD(part, 0x4E);    // xor2
            part = DPP_ADD(part, 0x141);   // row_half_mirror
            part = DPP_ADD(part, 0x140);   // row_mirror -> 16-lane sum
            float p = exp2f(part);         // att prescaled: == exp(score)
            l += p;
            a0 += p * x0; a1 += p * x1; a2 += p * x2; a3 += p * x3;
        };

        body(uself);                              // implicit self-loop (always live)
        int e = e0;
        for (; e + 4 <= e1; e += 4) {
            int c0 = col[e], c1 = col[e + 1], c2 = col[e + 2], c3 = col[e + 3];
            ushort4 u0 = ld(c0), u1 = ld(c1), u2 = ld(c2), u3 = ld(c3);
            body(u0); body(u1); body(u2); body(u3);
        }
        int rem = e1 - e;
        if (rem > 0) {
            int c0 = col[e];
            int c1 = (rem > 1) ? col[e + 1] : c0;
            int c2 = (rem > 2) ? col[e + 2] : c0;
            ushort4 u0 = ld(c0), u1 = ld(c1), u2 = ld(c2);
            body(u0);
            if (rem > 1) body(u1);
            if (rem > 2) body(u2);
        }

        float inv = __builtin_amdgcn_rcpf(l);     // l>0 (self-loop alive); approx ok
        float t0 = a0 * inv + bcv.x;
        float t1 = a1 * inv + bcv.y;
        float t2 = a2 * inv + bcv.z;
        float t3 = a3 * inv + bcv.w;
        t0 += __shfl_xor(t0, 16, 64); t0 += __shfl_xor(t0, 32, 64);
        t1 += __shfl_xor(t1, 16, 64); t1 += __shfl_xor(t1, 32, 64);
        t2 += __shfl_xor(t2, 16, 64); t2 += __shfl_xor(t2, 32, 64);
        t3 += __shfl_xor(t3, 16, 64); t3 += __shfl_xor(t3, 32, 64);
        if (lane < 16) {
            ushort4 o;
            o.x = f2b(tanhf(t0)); o.y = f2b(tanhf(t1));
            o.z = f2b(tanhf(t2)); o.w = f2b(tanhf(t3));
            *(ushort4*)(h + (size_t)node * HID + lane * 4) = o;
        }

        if (!more) return;
        idx = nidx; node = nnode;
        re = re_n; xru = xru_n; uself = uself_n;
    }
}

// ---------------------------------------------------------------- out = (h @ Wg + bg) * (cs>0), 32 nodes/block
__global__ __launch_bounds__(256) void k_out(const bf16_t* __restrict__ h,
                                             const float* __restrict__ Wg,
                                             const float* __restrict__ bg,
                                             const int* __restrict__ cs,
                                             void* __restrict__ out,
                                             const int* __restrict__ flag) {
    __shared__ float Ws[HID * OUTD];
    __shared__ float bs[OUTD];
    int t = threadIdx.x;
    for (int i = t; i < HID * OUTD; i += 256) Ws[i] = Wg[i];
    if (t < OUTD) bs[t] = bg[t];
    __syncthreads();
    int g0 = t >> 5, c = t & 31;
    int fl = *flag;
#pragma unroll
    for (int g = 0; g < 4; g++) {
        int node = blockIdx.x * 32 + g * 8 + g0;
        if (node >= NN) break;
        float res = 0.f;
        if (cs[node] > 0) {
            const short8* hr8 = (const short8*)(h + (size_t)node * HID);
            float acc = bs[c];
#pragma unroll
            for (int j = 0; j < 8; j++) {
                short8 hv = hr8[j];
#pragma unroll
                for (int k = 0; k < 8; k++)
                    acc += b2f((bf16_t)hv[k]) * Ws[(j * 8 + k) * OUTD + c];
            }
            res = acc;
        }
        size_t idx = (size_t)node * OUTD + c;
        if (fl) ((bf16_t*)out)[idx] = f2b(res);
        else    ((float*)out)[idx]  = res;
    }
}

// ---------------------------------------------------------------- host
static inline size_t alignup(size_t x) { return (x + 255) & ~(size_t)255; }

extern "C" void kernel_launch(void* const* d_in, const int* in_sizes, int n_in,
                              void* d_out, int out_size, void* d_ws, size_t ws_size,
                              hipStream_t stream) {
    const void* feat_raw  = d_in[0];
    const void* W_in_raw  = d_in[1];
    const void* b_in_raw  = d_in[2];
    const void* Wl_raw    = d_in[3];
    const void* bl_raw    = d_in[4];
    const void* Wr_raw    = d_in[5];
    const void* br_raw    = d_in[6];
    const void* att_raw   = d_in[7];
    const void* bconv_raw = d_in[8];
    const void* Wg_raw    = d_in[9];
    const void* bg_raw    = d_in[10];
    const int* edge       = (const int*)d_in[11];    // [2][EE]: src row, dst row
    const int* nmask      = (const int*)d_in[12];
    const int* cstate     = (const int*)d_in[13];

    const int* e_src = edge;
    const int* e_dst = edge + EE;

    const size_t SZ_HB   = alignup((size_t)NN * HID * sizeof(bf16_t));
    const size_t SZ_X    = alignup((size_t)NN * 256 * sizeof(bf16_t));
    const size_t SZ_I4   = alignup((size_t)NN * 4 * sizeof(int));   // deg4/cur4/rend4
    const size_t SZ_I    = alignup((size_t)NN * sizeof(int));
    const size_t SZ_COL  = alignup((size_t)EE * sizeof(int));
    const int nch = (NN + 1023) / 1024;
    const size_t SZ_WT   = alignup((size_t)512 * 128 * sizeof(bf16_t));
    const size_t SZ_WTS  = alignup((size_t)512 * 64 * sizeof(bf16_t));
    const size_t SZ_B    = alignup(512 * sizeof(float));
    const size_t SZ_WG   = alignup((size_t)HID * OUTD * sizeof(float));

    char* w = (char*)d_ws;
    bf16_t* h0   = (bf16_t*)w; w += SZ_HB;
    bf16_t* h    = (bf16_t*)w; w += SZ_HB;
    bf16_t* xl   = (bf16_t*)w; w += SZ_X;
    bf16_t* xr   = (bf16_t*)w; w += SZ_X;
    int* deg4    = (int*)w;    w += SZ_I4;
    int* mbuf    = (int*)w;    w += 256;     // 64 ints; adjacent to deg4 (one memset)
    int* cls     = (int*)w;    w += 512;     // clscnt[64] | clscur[64]; also in memset
    int* cur4    = (int*)w;    w += SZ_I4;
    int* rend4   = (int*)w;    w += SZ_I4;
    int* colA    = (int*)w;    w += SZ_COL;
    int* order   = (int*)w;    w += SZ_I;
    bf16_t* Wt   = (bf16_t*)w; w += SZ_WT;
    bf16_t* WtS  = (bf16_t*)w; w += SZ_WTS;
    float* bb    = (float*)w;  w += SZ_B;
    float* attf  = (float*)w;  w += SZ_B;
    float* bcf   = (float*)w;  w += SZ_B;
    float* Wgf   = (float*)w;  w += SZ_WG;
    float* bgf   = (float*)w;  w += SZ_B;
    int* flag    = (int*)w;    w += 256;
    if ((size_t)(w - (char*)d_ws) > ws_size) return;

    int* clscnt = cls;
    int* clscur = cls + 64;

    // ---- zero deg4 + mbuf + cls in one async memset (they are adjacent)
    hipMemsetAsync(deg4, 0, SZ_I4 + 256 + 512, stream);

    // ---- fused setup: flag + weights + edge hist + h0
    k_setup<<<267 + EB + H0_BLOCKS, 256, 0, stream>>>(
        W_in_raw, b_in_raw, att_raw, bconv_raw, Wg_raw, bg_raw,
        Wl_raw, Wr_raw, bl_raw, br_raw, feat_raw, nmask, e_src, e_dst,
        attf, bcf, Wgf, bgf, Wt, WtS, bb, deg4, flag, h0, h);

    // ---- CSR (bucket-sorted) + class histogram
    k_scan<<<nch, 256, 0, stream>>>(deg4, nmask, cur4, rend4, clscnt, NN);
    // ---- scatter cols + degree-stratified order + step counts
    k_scatter_all<<<(EE + 255) / 256, 256, 0, stream>>>(e_src, e_dst, cur4, colA,
                                                        nmask, rend4, clscnt, clscur,
                                                        mbuf, order);

    // ---- step 0: K=64 gemm with pre-summed weights (h==h0), then agg
    k_gemm0<<<dim3((NN + 63) / 64, 4), 256, 0, stream>>>(h0, WtS, bb, xl, xr, order, mbuf);
    k_agg<<<2048, 256, 0, stream>>>(h, xl, xr, attf, bcf, rend4, colA, order, mbuf, 0);

    // ---- steps 1,2: K=128 gemm + agg
    for (int s = 1; s < TSTEPS; s++) {
        k_gemm_mfma<<<dim3((NN + 63) / 64, 4), 256, 0, stream>>>(h, h0, Wt, bb, xl, xr,
                                                                 order, mbuf, s);
        k_agg<<<2048, 256, 0, stream>>>(h, xl, xr, attf, bcf,
                                        rend4, colA, order, mbuf, s);
    }

    // ---- epilogue
    k_out<<<(NN + 31) / 32, 256, 0, stream>>>(h, Wgf, bgf, cstate, d_out, flag);
}

// Round 6
// 278.346 us; speedup vs baseline: 1.3879x; 1.3879x over previous
//
#include <hip/hip_runtime.h>
#include <hip/hip_bf16.h>

// Problem constants (from reference)
#define NN      50000
#define EE      200000
#define IN_DIM  32
#define HID     64
#define HEADS   4
#define OUTD    32
#define TSTEPS  3

typedef unsigned short bf16_t;
typedef __attribute__((ext_vector_type(8))) short  short8;
typedef __attribute__((ext_vector_type(4))) float  floatx4;

__device__ __forceinline__ float b2f(bf16_t u) {
    union { unsigned int i; float f; } v; v.i = ((unsigned int)u) << 16; return v.f;
}
__device__ __forceinline__ bf16_t f2b(float f) {
    union { float f; unsigned int i; } v; v.f = f;
    unsigned int r = v.i + 0x7FFF + ((v.i >> 16) & 1);   // RNE
    return (bf16_t)(r >> 16);
}

// DPP-based add of a lane-permuted copy (all lanes valid, bound_ctrl=1).
// 0xB1=quad_perm[1,0,3,2](xor1), 0x4E=quad_perm[2,3,0,1](xor2),
// 0x141=row_half_mirror, 0x140=row_mirror. Chain of 4 = sum over each 16-lane group.
#define DPP_ADD(x, ctrl) ((x) + __int_as_float(                                 \
        __builtin_amdgcn_update_dpp(0, __float_as_int(x), (ctrl), 0xF, 0xF, true)))

#define H0_BLOCKS ((NN + 63) / 64)   // h0 section: 64 nodes/block
#define NB_NODE   ((NN + 255) / 256) // 196 blocks covering node range
#define NBC       (NB_NODE * 4)      // bcount entries
#define EB        ((EE + 1023) / 1024) // edge-hist blocks (4 edges/thread)

// ---------------------------------------------------------------- fused setup (+h0 +bucket counts +edge hist)
__global__ __launch_bounds__(256) void k_setup(
        const void* W_in, const void* b_in, const void* att, const void* bconv,
        const void* Wg, const void* bg,
        const void* Wl_raw, const void* Wr_raw, const void* bl_raw, const void* br_raw,
        const void* feat_raw, const int* __restrict__ nmask,
        const int* __restrict__ e_src, const int* __restrict__ e_dst,
        float* attf, float* bcf, float* Wgf, float* bgf,
        bf16_t* __restrict__ Wt, bf16_t* __restrict__ WtS, float* __restrict__ bb,
        int* __restrict__ deg4, int* __restrict__ flag, int* __restrict__ bcount,
        bf16_t* __restrict__ h0, bf16_t* __restrict__ h) {
    __shared__ int bad;
    __shared__ float Ws[IN_DIM * HID];
    __shared__ float bs[HID];
    __shared__ int wcnt[4][4];
    int t = threadIdx.x, bid = blockIdx.x;
    if (t == 0) bad = 0;
    __syncthreads();
    {
        const bf16_t* p = (const bf16_t*)W_in;
        int mybad = 0;
        for (int i = t; i < IN_DIM * HID; i += 256) {
            float v = b2f(p[i]);
            if (v != v || fabsf(v) > 100.f) mybad = 1;
        }
        if (mybad) atomicOr(&bad, 1);
    }
    __syncthreads();
    int f = bad ? 0 : 1;
    if (bid == 0 && t == 0) *flag = f;

    if (bid < 256) {
        int i = bid * 256 + t;              // over 512*128
        int n = i >> 7, k = i & 127;
        const void* W = (n < 256) ? Wl_raw : Wr_raw;
        int nn = (n < 256) ? n : n - 256;
        float v = f ? b2f(((const bf16_t*)W)[k * 256 + nn])
                    : ((const float*)W)[k * 256 + nn];
        Wt[n * 128 + k] = f2b(v);
        if (k < 64) {
            float v2 = f ? b2f(((const bf16_t*)W)[(k + 64) * 256 + nn])
                         : ((const float*)W)[(k + 64) * 256 + nn];
            WtS[n * 64 + k] = f2b(v + v2);   // step-0 weights: x=[h0|h0]
        }
        if (k == 0) {
            const void* b = (n < 256) ? bl_raw : br_raw;
            bb[n] = f ? b2f(((const bf16_t*)b)[nn]) : ((const float*)b)[nn];
        }
    } else if (bid < 267) {
        int i = (bid - 256) * 256 + t;      // over 2592
        const void* src; float* dst; int off;
        if      (i < 256)  { src = att;   dst = attf; off = i; }
        else if (i < 512)  { src = bconv; dst = bcf;  off = i - 256; }
        else if (i < 2560) { src = Wg;    dst = Wgf;  off = i - 512; }
        else if (i < 2592) { src = bg;    dst = bgf;  off = i - 2560; }
        else return;
        dst[off] = f ? b2f(((const bf16_t*)src)[off]) : ((const float*)src)[off];
    } else if (bid < 267 + NB_NODE) {
        // per-block mask-bucket counts (deg4 zeroed by host memset)
        int nb = bid - 267;
        int i = nb * 256 + t;
        bool valid = i < NN;
        int wid = t >> 6, lane = t & 63;
        int v = 0;
        if (valid) { int m = nmask[i]; v = m < 0 ? 0 : (m > 3 ? 3 : m); }
#pragma unroll
        for (int b = 0; b < 4; b++) {
            unsigned long long mm = __ballot(valid && v == b);
            if (lane == 0) wcnt[wid][b] = __popcll(mm);
        }
        __syncthreads();
        if (t < 4)
            bcount[nb * 4 + t] = wcnt[0][t] + wcnt[1][t] + wcnt[2][t] + wcnt[3][t];
    } else if (bid < 267 + NB_NODE + EB) {
        // edge histogram: per-(dst, src-mask-bucket) degree
        int nb = bid - 267 - NB_NODE;
        int i = (nb * 256 + t) * 4;
        if (i + 3 < EE) {
            int4 dv = *(const int4*)(e_dst + i);
            int4 sv = *(const int4*)(e_src + i);
            int m0 = nmask[sv.x]; m0 = m0 < 0 ? 0 : (m0 > 3 ? 3 : m0);
            int m1 = nmask[sv.y]; m1 = m1 < 0 ? 0 : (m1 > 3 ? 3 : m1);
            int m2 = nmask[sv.z]; m2 = m2 < 0 ? 0 : (m2 > 3 ? 3 : m2);
            int m3 = nmask[sv.w]; m3 = m3 < 0 ? 0 : (m3 > 3 ? 3 : m3);
            atomicAdd(&deg4[dv.x * 4 + m0], 1);
            atomicAdd(&deg4[dv.y * 4 + m1], 1);
            atomicAdd(&deg4[dv.z * 4 + m2], 1);
            atomicAdd(&deg4[dv.w * 4 + m3], 1);
        } else {
            for (; i < EE; i++) {
                int s = e_src[i];
                int m = nmask[s]; m = m < 0 ? 0 : (m > 3 ? 3 : m);
                atomicAdd(&deg4[e_dst[i] * 4 + m], 1);
            }
        }
    } else {
        // h0: stage W_in/b_in once, then 16 groups x 4 nodes = 64 nodes/block
        for (int i = t; i < IN_DIM * HID; i += 256)
            Ws[i] = f ? b2f(((const bf16_t*)W_in)[i]) : ((const float*)W_in)[i];
        if (t < HID)
            bs[t] = f ? b2f(((const bf16_t*)b_in)[t]) : ((const float*)b_in)[t];
        __syncthreads();
        int nb = bid - (267 + NB_NODE + EB);
        int wid = t >> 6, c = t & 63;
#pragma unroll
        for (int g = 0; g < 16; g++) {
            int node = (nb * 16 + g) * 4 + wid;
            if (node >= NN) break;
            float acc = bs[c];
            if (f) {
                const short8* fr8 = (const short8*)((const bf16_t*)feat_raw
                                                    + (size_t)node * IN_DIM);
#pragma unroll
                for (int j = 0; j < 4; j++) {
                    short8 fv = fr8[j];
#pragma unroll
                    for (int k = 0; k < 8; k++)
                        acc += b2f((bf16_t)fv[k]) * Ws[(j * 8 + k) * HID + c];
                }
            } else {
                const float4* fr4 = (const float4*)((const float*)feat_raw
                                                    + (size_t)node * IN_DIM);
#pragma unroll
                for (int j = 0; j < 8; j++) {
                    float4 fv = fr4[j];
                    acc += fv.x * Ws[(j * 4 + 0) * HID + c];
                    acc += fv.y * Ws[(j * 4 + 1) * HID + c];
                    acc += fv.z * Ws[(j * 4 + 2) * HID + c];
                    acc += fv.w * Ws[(j * 4 + 3) * HID + c];
                }
            }
            bf16_t o = f2b(acc);
            h0[(size_t)node * HID + c] = o;
            h [(size_t)node * HID + c] = o;
        }
    }
}

// ---------------------------------------------------------------- single-kernel scan over deg4
__global__ __launch_bounds__(256) void k_scan(const int* __restrict__ deg4,
                                              int* __restrict__ cur4,
                                              int* __restrict__ rend4,
                                              const int* __restrict__ bcount,
                                              int* __restrict__ mbuf,
                                              int n, int nch) {
    __shared__ int sc[256];
    __shared__ int spre[256];
    __shared__ int cb[4];
    int t = threadIdx.x, bid = blockIdx.x;

    if (bid == 0) {
        if (t < 4) cb[t] = 0;
        __syncthreads();
        for (int i = t; i < NBC; i += 256) atomicAdd(&cb[i & 3], bcount[i]);
        __syncthreads();
        if (t == 0) {
            int c1 = cb[1], c2 = cb[2], c3 = cb[3];
            mbuf[7] = 0;              // order bucket 3 cursor
            mbuf[6] = c3;             // bucket 2
            mbuf[5] = c3 + c2;        // bucket 1
            mbuf[4] = c3 + c2 + c1;   // bucket 0
            mbuf[8] = c3 + c2 + c1;   // active at step 0
            mbuf[9] = c3 + c2;        // step 1
            mbuf[10] = c3;            // step 2
        }
    }

    const int4* d4 = (const int4*)deg4;   // one int4 = one node's 4 bucket degrees
    int base = bid * 1024;
    // global prefix of all nodes before this chunk
    int pre = 0;
    for (int i = t; i < base; i += 256) {
        int4 q = d4[i];
        pre += q.x + q.y + q.z + q.w;
    }
    spre[t] = pre; __syncthreads();
    for (int off = 128; off > 0; off >>= 1) {
        if (t < off) spre[t] += spre[t + off];
        __syncthreads();
    }
    int bpref = spre[0];

    int4 dd[4]; int tot[4]; int s = 0;
#pragma unroll
    for (int j = 0; j < 4; j++) {
        int i = base + t * 4 + j;
        if (i < n) dd[j] = d4[i];
        else { dd[j].x = 0; dd[j].y = 0; dd[j].z = 0; dd[j].w = 0; }
        tot[j] = dd[j].x + dd[j].y + dd[j].z + dd[j].w;
        s += tot[j];
    }
    sc[t] = s; __syncthreads();
    for (int off = 1; off < 256; off <<= 1) {
        int add = (t >= off) ? sc[t - off] : 0;
        __syncthreads();
        sc[t] += add;
        __syncthreads();
    }
    int run = sc[t] - s + bpref;
#pragma unroll
    for (int j = 0; j < 4; j++) {
        int i = base + t * 4 + j;
        if (i < n) {
            int c3 = run;                 // start of bucket 3
            int c2 = c3 + dd[j].w;        // start of bucket 2
            int c1 = c2 + dd[j].z;        // start of bucket 1
            int c0 = c1 + dd[j].y;        // start of bucket 0
            int4 cu; cu.x = c0; cu.y = c1; cu.z = c2; cu.w = c3;
            *(int4*)(cur4 + i * 4) = cu;
            int4 re; re.x = c0; re.y = c1; re.z = c2; re.w = run;  // ends + row start
            *(int4*)(rend4 + i * 4) = re;
        }
        run += tot[j];
    }
}

// ---------------------------------------------------------------- scatter: bucket-sorted CSR cols + compaction order
__global__ __launch_bounds__(256) void k_scatter_all(const int* __restrict__ src,
                                                     const int* __restrict__ dst,
                                                     int* __restrict__ cur4,
                                                     int* __restrict__ col,
                                                     const int* __restrict__ mask,
                                                     int* __restrict__ mbuf,
                                                     int* __restrict__ order) {
    int t = threadIdx.x, bid = blockIdx.x;
    int i = bid * 256 + t;
    if (i < EE) {
        int sv = src[i];
        int m = mask[sv]; m = m < 0 ? 0 : (m > 3 ? 3 : m);
        int d = dst[i];
        int pos = atomicAdd(&cur4[d * 4 + m], 1);
        col[pos] = sv;                       // bucket-sorted: no mask packing needed
    }
    if (bid < NB_NODE) {
        __shared__ int wcnt[4][4];
        __shared__ int bbase[4];
        int wid = t >> 6, lane = t & 63;
        int ni = bid * 256 + t;
        bool valid = ni < NN;
        int v = 0;
        if (valid) { int m = mask[ni]; v = m < 0 ? 0 : (m > 3 ? 3 : m); }
        int rank = 0;
#pragma unroll
        for (int b = 0; b < 4; b++) {
            unsigned long long mm = __ballot(valid && v == b);
            if (valid && v == b)
                rank = __popcll(mm & ((lane == 0) ? 0ull : (~0ull >> (64 - lane))));
            if (lane == 0) wcnt[wid][b] = __popcll(mm);
        }
        __syncthreads();
        if (t < 4) {
            int tot = wcnt[0][t] + wcnt[1][t] + wcnt[2][t] + wcnt[3][t];
            bbase[t] = atomicAdd(&mbuf[4 + t], tot);   // one atomic/bucket/block
        }
        __syncthreads();
        if (valid) {
            int wpre = 0;
            for (int ww = 0; ww < wid; ww++) wpre += wcnt[ww][v];
            order[bbase[v] + wpre + rank] = ni;
        }
    }
}

// ---------------------------------------------------------------- step-0 MFMA GEMM (K=64, pre-summed weights)
__global__ __launch_bounds__(256) void k_gemm0(const bf16_t* __restrict__ h0,
                                               const bf16_t* __restrict__ WtS,
                                               const float* __restrict__ bb,
                                               bf16_t* __restrict__ xl,
                                               bf16_t* __restrict__ xr,
                                               const int* __restrict__ order,
                                               const int* __restrict__ mbuf) {
    int count = mbuf[8];
    int mbase = blockIdx.x * 64;
    if (mbase >= count) return;

    __shared__ bf16_t smem[64 * 72 + 128 * 72];   // 27.6 KB
    bf16_t* As = smem;
    bf16_t* Bs = smem + 64 * 72;
    bf16_t* Cs = smem;                             // 64*136=8704 <= 13824

    int t = threadIdx.x;
    int nbase = blockIdx.y * 128;

    {
        int ln = t >> 2, lq = t & 3;
        int idx = mbase + ln;
        int node = (idx < count) ? order[idx] : -1;
        ulonglong2 z; z.x = 0; z.y = 0;
        ulonglong2 v0 = z, v1 = z;
        if (node >= 0) {
            v0 = *(const ulonglong2*)(h0 + (size_t)node * HID + lq * 16);
            v1 = *(const ulonglong2*)(h0 + (size_t)node * HID + lq * 16 + 8);
        }
        *(ulonglong2*)(&As[ln * 72 + lq * 16]) = v0;
        *(ulonglong2*)(&As[ln * 72 + lq * 16 + 8]) = v1;
    }
    {
        int n = t >> 1, kc = (t & 1) * 32;
        const bf16_t* srcp = WtS + (size_t)(nbase + n) * 64 + kc;
        bf16_t* dstp = &Bs[n * 72 + kc];
        *(ulonglong2*)(dstp)      = *(const ulonglong2*)(srcp);
        *(ulonglong2*)(dstp + 8)  = *(const ulonglong2*)(srcp + 8);
        *(ulonglong2*)(dstp + 16) = *(const ulonglong2*)(srcp + 16);
        *(ulonglong2*)(dstp + 24) = *(const ulonglong2*)(srcp + 24);
    }
    __syncthreads();

    int wv = t >> 6, lane = t & 63, mrow = lane & 15, quad = lane >> 4;
    floatx4 acc[8];
#pragma unroll
    for (int nf = 0; nf < 8; nf++) acc[nf] = (floatx4){0.f, 0.f, 0.f, 0.f};
#pragma unroll
    for (int kq = 0; kq < 2; kq++) {
        short8 a = *(const short8*)(&As[(wv * 16 + mrow) * 72 + kq * 32 + quad * 8]);
#pragma unroll
        for (int nf = 0; nf < 8; nf++) {
            short8 b = *(const short8*)(&Bs[(nf * 16 + mrow) * 72 + kq * 32 + quad * 8]);
            acc[nf] = __builtin_amdgcn_mfma_f32_16x16x32_bf16(a, b, acc[nf], 0, 0, 0);
        }
    }
    __syncthreads();

#pragma unroll
    for (int nf = 0; nf < 8; nf++) {
        float bv = bb[nbase + nf * 16 + mrow];
#pragma unroll
        for (int r = 0; r < 4; r++) {
            int m = wv * 16 + quad * 4 + r;
            Cs[m * 136 + nf * 16 + mrow] = f2b(acc[nf][r] + bv);
        }
    }
    __syncthreads();

    bf16_t* outp = (blockIdx.y < 2) ? xl : xr;
    int cc = (blockIdx.y & 1) * 128;
#pragma unroll
    for (int i = 0; i < 4; i++) {
        int c = t + i * 256;
        int m = c >> 4, kc = (c & 15) * 8;
        int idx = mbase + m;
        if (idx < count) {
            int node = order[idx];
            *(ulonglong2*)(outp + (size_t)node * 256 + cc + kc) =
                *(const ulonglong2*)(&Cs[m * 136 + kc]);
        }
    }
}

// ---------------------------------------------------------------- steps 1-2 MFMA GEMM (K=128)
__global__ __launch_bounds__(256) void k_gemm_mfma(const bf16_t* __restrict__ h,
                                                   const bf16_t* __restrict__ h0,
                                                   const bf16_t* __restrict__ Wt,
                                                   const float* __restrict__ bb,
                                                   bf16_t* __restrict__ xl,
                                                   bf16_t* __restrict__ xr,
                                                   const int* __restrict__ order,
                                                   const int* __restrict__ mbuf,
                                                   int step) {
    int count = mbuf[8 + step];
    int mbase = blockIdx.x * 64;
    if (mbase >= count) return;

    __shared__ bf16_t smem[64 * 136 + 128 * 136];   // 52 KB
    bf16_t* As = smem;
    bf16_t* Bs = smem + 64 * 136;
    bf16_t* Cs = smem;

    int t = threadIdx.x;
    int nbase = blockIdx.y * 128;

    {
        int ln = t >> 2, lq = t & 3;
        int idx = mbase + ln;
        int node = (idx < count) ? order[idx] : -1;
        ulonglong2 z; z.x = 0; z.y = 0;
#pragma unroll
        for (int j = 0; j < 2; j++) {
            int chunk = lq + j * 4;
            ulonglong2 vh = z, vh0 = z;
            if (node >= 0) {
                vh  = *(const ulonglong2*)(h  + (size_t)node * HID + chunk * 8);
                vh0 = *(const ulonglong2*)(h0 + (size_t)node * HID + chunk * 8);
            }
            *(ulonglong2*)(&As[ln * 136 + chunk * 8]) = vh;
            *(ulonglong2*)(&As[ln * 136 + 64 + chunk * 8]) = vh0;
        }
    }
#pragma unroll
    for (int i = 0; i < 8; i++) {
        int c = t + i * 256;
        int n = c >> 4, kc = (c & 15) * 8;
        *(ulonglong2*)(&Bs[n * 136 + kc]) =
            *(const ulonglong2*)(Wt + (size_t)(nbase + n) * 128 + kc);
    }
    __syncthreads();

    int wv = t >> 6, lane = t & 63, mrow = lane & 15, quad = lane >> 4;
    floatx4 acc[8];
#pragma unroll
    for (int nf = 0; nf < 8; nf++) acc[nf] = (floatx4){0.f, 0.f, 0.f, 0.f};
#pragma unroll
    for (int kq = 0; kq < 4; kq++) {
        short8 a = *(const short8*)(&As[(wv * 16 + mrow) * 136 + kq * 32 + quad * 8]);
#pragma unroll
        for (int nf = 0; nf < 8; nf++) {
            short8 b = *(const short8*)(&Bs[(nf * 16 + mrow) * 136 + kq * 32 + quad * 8]);
            acc[nf] = __builtin_amdgcn_mfma_f32_16x16x32_bf16(a, b, acc[nf], 0, 0, 0);
        }
    }
    __syncthreads();

#pragma unroll
    for (int nf = 0; nf < 8; nf++) {
        float bv = bb[nbase + nf * 16 + mrow];
#pragma unroll
        for (int r = 0; r < 4; r++) {
            int m = wv * 16 + quad * 4 + r;
            Cs[m * 136 + nf * 16 + mrow] = f2b(acc[nf][r] + bv);
        }
    }
    __syncthreads();

    bf16_t* outp = (blockIdx.y < 2) ? xl : xr;
    int cc = (blockIdx.y & 1) * 128;
#pragma unroll
    for (int i = 0; i < 4; i++) {
        int c = t + i * 256;
        int m = c >> 4, kc = (c & 15) * 8;
        int idx = mbase + m;
        if (idx < count) {
            int node = order[idx];
            *(ulonglong2*)(outp + (size_t)node * 256 + cc + kc) =
                *(const ulonglong2*)(&Cs[m * 136 + kc]);
        }
    }
}

// ---------------------------------------------------------------- segment softmax + aggregate (in-place bf16 h)
// Full-depth software pipeline across nodes: rotate not just {order,rend4,xr,self}
// (R4) but also the first col-quad and first 4 xl rows of the next node — the
// complete 4-deep dependent chain issues during current node's compute.
// Over-reads past e1 are guarded at USE; col[e0n..e0n+3] may read ≤12B past the
// col array into the adjacent order[] buffer (valid node ids, loads are safe).
// Template STEP -> three distinct kernel symbols for per-step profiler visibility.
template<int STEP>
__global__ __launch_bounds__(256) void k_agg(bf16_t* __restrict__ h,
                                             const bf16_t* __restrict__ xl,
                                             const bf16_t* __restrict__ xr,
                                             const float* __restrict__ att,
                                             const float* __restrict__ b_conv,
                                             const int* __restrict__ rend4,
                                             const int* __restrict__ col,
                                             const int* __restrict__ order,
                                             const int* __restrict__ mbuf) {
    int count = mbuf[8 + STEP];
    int wid = threadIdx.x >> 6;
    int lane = threadIdx.x & 63;
    const int stride = gridDim.x * 4;
    float4 attv = *(const float4*)(att + lane * 4);
    // prescale by log2(e): exp(score) == exp2(score_scaled)
    attv.x *= 1.44269504f; attv.y *= 1.44269504f;
    attv.z *= 1.44269504f; attv.w *= 1.44269504f;
    float4 bcv  = *(const float4*)(b_conv + lane * 4);

    auto ld = [&](int s) {
        return *(const ushort4*)(xl + (size_t)s * 256 + lane * 4);
    };
    auto epick = [](int4 r) {
        return (STEP == 0) ? r.x : (STEP == 1) ? r.y : r.z;
    };

    int idx = blockIdx.x * 4 + wid;
    if (idx >= count) return;

    // ---- preamble + first col/row quad for the first node (exposed once)
    int node = order[idx];
    int4 re = *(const int4*)(rend4 + node * 4);
    ushort4 xru   = *(const ushort4*)(xr + (size_t)node * 256 + lane * 4);
    ushort4 uself = *(const ushort4*)(xl + (size_t)node * 256 + lane * 4);
    int e0 = re.w, e1 = epick(re);
    int c0 = col[e0], c1 = col[e0 + 1], c2 = col[e0 + 2], c3 = col[e0 + 3];
    ushort4 u0 = ld(c0), u1 = ld(c1), u2 = ld(c2), u3 = ld(c3);

    for (;;) {
        // ---- issue next node's FULL chain now (hidden under current compute)
        int nidx = idx + stride;
        bool more = nidx < count;
        int nnode = order[more ? nidx : idx];
        int4 re_n = *(const int4*)(rend4 + nnode * 4);
        ushort4 xru_n   = *(const ushort4*)(xr + (size_t)nnode * 256 + lane * 4);
        ushort4 uself_n = *(const ushort4*)(xl + (size_t)nnode * 256 + lane * 4);
        int e0n = re_n.w, e1n = epick(re_n);
        int cn0 = col[e0n], cn1 = col[e0n + 1], cn2 = col[e0n + 2], cn3 = col[e0n + 3];
        ushort4 un0 = ld(cn0), un1 = ld(cn1), un2 = ld(cn2), un3 = ld(cn3);

        // ---- process current node (first quad already in registers)
        float xr0 = b2f(xru.x), xr1 = b2f(xru.y), xr2 = b2f(xru.z), xr3 = b2f(xru.w);
        float a0 = 0.f, a1 = 0.f, a2 = 0.f, a3 = 0.f, l = 0.f;

        auto body = [&](ushort4 xu) {
            float x0 = b2f(xu.x), x1 = b2f(xu.y), x2 = b2f(xu.z), x3 = b2f(xu.w);
            float v0 = x0 + xr0; v0 = fmaxf(v0, 0.2f * v0);
            float v1 = x1 + xr1; v1 = fmaxf(v1, 0.2f * v1);
            float v2 = x2 + xr2; v2 = fmaxf(v2, 0.2f * v2);
            float v3 = x3 + xr3; v3 = fmaxf(v3, 0.2f * v3);
            float part = attv.x * v0 + attv.y * v1 + attv.z * v2 + attv.w * v3;
            part = DPP_ADD(part, 0xB1);    // xor1
            part = DPP_ADD(part, 0x4E);    // xor2
            part = DPP_ADD(part, 0x141);   // row_half_mirror
            part = DPP_ADD(part, 0x140);   // row_mirror -> 16-lane sum
            float p = exp2f(part);         // att prescaled: == exp(score)
            l += p;
            a0 += p * x0; a1 += p * x1; a2 += p * x2; a3 += p * x3;
        };

        body(uself);                              // implicit self-loop (always live)
        int nl = e1 - e0;                         // live edge count (wave-uniform)
        if (nl > 0) body(u0);
        if (nl > 1) body(u1);
        if (nl > 2) body(u2);
        if (nl > 3) body(u3);
        // rows beyond the prefetched quad (nl > 4): classic batched loop
        int e = e0 + 4;
        for (; e + 4 <= e1; e += 4) {
            int d0 = col[e], d1 = col[e + 1], d2 = col[e + 2], d3 = col[e + 3];
            ushort4 v0 = ld(d0), v1 = ld(d1), v2 = ld(d2), v3 = ld(d3);
            body(v0); body(v1); body(v2); body(v3);
        }
        int rem = e1 - e;
        if (rem > 0) {
            int d0 = col[e];
            int d1 = (rem > 1) ? col[e + 1] : d0;
            int d2 = (rem > 2) ? col[e + 2] : d0;
            ushort4 v0 = ld(d0), v1 = ld(d1), v2 = ld(d2);
            body(v0);
            if (rem > 1) body(v1);
            if (rem > 2) body(v2);
        }

        float inv = __builtin_amdgcn_rcpf(l);     // l>0 (self-loop alive); approx ok
        float t0 = a0 * inv + bcv.x;
        float t1 = a1 * inv + bcv.y;
        float t2 = a2 * inv + bcv.z;
        float t3 = a3 * inv + bcv.w;
        t0 += __shfl_xor(t0, 16, 64); t0 += __shfl_xor(t0, 32, 64);
        t1 += __shfl_xor(t1, 16, 64); t1 += __shfl_xor(t1, 32, 64);
        t2 += __shfl_xor(t2, 16, 64); t2 += __shfl_xor(t2, 32, 64);
        t3 += __shfl_xor(t3, 16, 64); t3 += __shfl_xor(t3, 32, 64);
        if (lane < 16) {
            ushort4 o;
            o.x = f2b(tanhf(t0)); o.y = f2b(tanhf(t1));
            o.z = f2b(tanhf(t2)); o.w = f2b(tanhf(t3));
            *(ushort4*)(h + (size_t)node * HID + lane * 4) = o;
        }

        if (!more) return;
        idx = nidx; node = nnode;
        e0 = e0n; e1 = e1n;
        xru = xru_n; uself = uself_n;
        u0 = un0; u1 = un1; u2 = un2; u3 = un3;
    }
}

// ---------------------------------------------------------------- out = (h @ Wg + bg) * (cs>0), 32 nodes/block
__global__ __launch_bounds__(256) void k_out(const bf16_t* __restrict__ h,
                                             const float* __restrict__ Wg,
                                             const float* __restrict__ bg,
                                             const int* __restrict__ cs,
                                             void* __restrict__ out,
                                             const int* __restrict__ flag) {
    __shared__ float Ws[HID * OUTD];
    __shared__ float bs[OUTD];
    int t = threadIdx.x;
    for (int i = t; i < HID * OUTD; i += 256) Ws[i] = Wg[i];
    if (t < OUTD) bs[t] = bg[t];
    __syncthreads();
    int g0 = t >> 5, c = t & 31;
    int fl = *flag;
#pragma unroll
    for (int g = 0; g < 4; g++) {
        int node = blockIdx.x * 32 + g * 8 + g0;
        if (node >= NN) break;
        float res = 0.f;
        if (cs[node] > 0) {
            const short8* hr8 = (const short8*)(h + (size_t)node * HID);
            float acc = bs[c];
#pragma unroll
            for (int j = 0; j < 8; j++) {
                short8 hv = hr8[j];
#pragma unroll
                for (int k = 0; k < 8; k++)
                    acc += b2f((bf16_t)hv[k]) * Ws[(j * 8 + k) * OUTD + c];
            }
            res = acc;
        }
        size_t idx = (size_t)node * OUTD + c;
        if (fl) ((bf16_t*)out)[idx] = f2b(res);
        else    ((float*)out)[idx]  = res;
    }
}

// ---------------------------------------------------------------- host
static inline size_t alignup(size_t x) { return (x + 255) & ~(size_t)255; }

extern "C" void kernel_launch(void* const* d_in, const int* in_sizes, int n_in,
                              void* d_out, int out_size, void* d_ws, size_t ws_size,
                              hipStream_t stream) {
    const void* feat_raw  = d_in[0];
    const void* W_in_raw  = d_in[1];
    const void* b_in_raw  = d_in[2];
    const void* Wl_raw    = d_in[3];
    const void* bl_raw    = d_in[4];
    const void* Wr_raw    = d_in[5];
    const void* br_raw    = d_in[6];
    const void* att_raw   = d_in[7];
    const void* bconv_raw = d_in[8];
    const void* Wg_raw    = d_in[9];
    const void* bg_raw    = d_in[10];
    const int* edge       = (const int*)d_in[11];    // [2][EE]: src row, dst row
    const int* nmask      = (const int*)d_in[12];
    const int* cstate     = (const int*)d_in[13];

    const int* e_src = edge;
    const int* e_dst = edge + EE;

    const size_t SZ_HB   = alignup((size_t)NN * HID * sizeof(bf16_t));
    const size_t SZ_X    = alignup((size_t)NN * 256 * sizeof(bf16_t));
    const size_t SZ_I4   = alignup((size_t)NN * 4 * sizeof(int));   // deg4/cur4/rend4
    const size_t SZ_I    = alignup((size_t)NN * sizeof(int));
    const size_t SZ_COL  = alignup((size_t)EE * sizeof(int));
    const int nch = (NN + 1023) / 1024;
    const size_t SZ_BC   = alignup((size_t)NBC * sizeof(int));
    const size_t SZ_WT   = alignup((size_t)512 * 128 * sizeof(bf16_t));
    const size_t SZ_WTS  = alignup((size_t)512 * 64 * sizeof(bf16_t));
    const size_t SZ_B    = alignup(512 * sizeof(float));
    const size_t SZ_WG   = alignup((size_t)HID * OUTD * sizeof(float));

    char* w = (char*)d_ws;
    bf16_t* h0   = (bf16_t*)w; w += SZ_HB;
    bf16_t* h    = (bf16_t*)w; w += SZ_HB;
    bf16_t* xl   = (bf16_t*)w; w += SZ_X;
    bf16_t* xr   = (bf16_t*)w; w += SZ_X;
    int* deg4    = (int*)w;    w += SZ_I4;
    int* mbuf    = (int*)w;    w += 256;     // adjacent to deg4: one memset covers both
    int* cur4    = (int*)w;    w += SZ_I4;
    int* rend4   = (int*)w;    w += SZ_I4;
    int* colA    = (int*)w;    w += SZ_COL;  // k_agg may over-read <=12B into order[]
    int* order   = (int*)w;    w += SZ_I;
    int* bcount  = (int*)w;    w += SZ_BC;
    bf16_t* Wt   = (bf16_t*)w; w += SZ_WT;
    bf16_t* WtS  = (bf16_t*)w; w += SZ_WTS;
    float* bb    = (float*)w;  w += SZ_B;
    float* attf  = (float*)w;  w += SZ_B;
    float* bcf   = (float*)w;  w += SZ_B;
    float* Wgf   = (float*)w;  w += SZ_WG;
    float* bgf   = (float*)w;  w += SZ_B;
    int* flag    = (int*)w;    w += 256;
    if ((size_t)(w - (char*)d_ws) > ws_size) return;

    // ---- zero deg4 + mbuf in one async memset (they are adjacent)
    hipMemsetAsync(deg4, 0, SZ_I4 + 256, stream);

    // ---- fused setup: flag + weights + bucket counts + edge hist + h0
    k_setup<<<267 + NB_NODE + EB + H0_BLOCKS, 256, 0, stream>>>(
        W_in_raw, b_in_raw, att_raw, bconv_raw, Wg_raw, bg_raw,
        Wl_raw, Wr_raw, bl_raw, br_raw, feat_raw, nmask, e_src, e_dst,
        attf, bcf, Wgf, bgf, Wt, WtS, bb, deg4, flag, bcount, h0, h);

    // ---- CSR (bucket-sorted) + compaction
    k_scan<<<nch, 256, 0, stream>>>(deg4, cur4, rend4, bcount, mbuf, NN, nch);
    k_scatter_all<<<(EE + 255) / 256, 256, 0, stream>>>(e_src, e_dst, cur4, colA,
                                                        nmask, mbuf, order);

    // ---- step 0: K=64 gemm with pre-summed weights (h==h0), then agg
    k_gemm0<<<dim3((NN + 63) / 64, 4), 256, 0, stream>>>(h0, WtS, bb, xl, xr, order, mbuf);
    k_agg<0><<<2048, 256, 0, stream>>>(h, xl, xr, attf, bcf, rend4, colA, order, mbuf);

    // ---- steps 1,2: K=128 gemm + agg
    k_gemm_mfma<<<dim3((NN + 63) / 64, 4), 256, 0, stream>>>(h, h0, Wt, bb, xl, xr,
                                                             order, mbuf, 1);
    k_agg<1><<<2048, 256, 0, stream>>>(h, xl, xr, attf, bcf, rend4, colA, order, mbuf);
    k_gemm_mfma<<<dim3((NN + 63) / 64, 4), 256, 0, stream>>>(h, h0, Wt, bb, xl, xr,
                                                             order, mbuf, 2);
    k_agg<2><<<2048, 256, 0, stream>>>(h, xl, xr, attf, bcf, rend4, colA, order, mbuf);

    // ---- epilogue
    k_out<<<(NN + 31) / 32, 256, 0, stream>>>(h, Wgf, bgf, cstate, d_out, flag);
}

// Round 7
// 277.080 us; speedup vs baseline: 1.3943x; 1.0046x over previous
//
#include <hip/hip_runtime.h>
#include <hip/hip_bf16.h>

// Problem constants (from reference)
#define NN      50000
#define EE      200000
#define IN_DIM  32
#define HID     64
#define HEADS   4
#define OUTD    32
#define TSTEPS  3

typedef unsigned short bf16_t;
typedef __attribute__((ext_vector_type(8))) short  short8;
typedef __attribute__((ext_vector_type(4))) float  floatx4;

__device__ __forceinline__ float b2f(bf16_t u) {
    union { unsigned int i; float f; } v; v.i = ((unsigned int)u) << 16; return v.f;
}
__device__ __forceinline__ bf16_t f2b(float f) {
    union { float f; unsigned int i; } v; v.f = f;
    unsigned int r = v.i + 0x7FFF + ((v.i >> 16) & 1);   // RNE
    return (bf16_t)(r >> 16);
}

// DPP-based add of a lane-permuted copy (all lanes valid, bound_ctrl=1).
// 0xB1=quad_perm[1,0,3,2](xor1), 0x4E=quad_perm[2,3,0,1](xor2),
// 0x141=row_half_mirror. Chain of 3 = sum over each 8-lane group.
#define DPP_ADD(x, ctrl) ((x) + __int_as_float(                                 \
        __builtin_amdgcn_update_dpp(0, __float_as_int(x), (ctrl), 0xF, 0xF, true)))

#define H0_BLOCKS ((NN + 63) / 64)   // h0 section: 64 nodes/block
#define NB_NODE   ((NN + 255) / 256) // 196 blocks covering node range
#define NBC       (NB_NODE * 4)      // bcount entries
#define EB        ((EE + 1023) / 1024) // edge-hist blocks (4 edges/thread)

// ---------------------------------------------------------------- fused setup (+h0 +bucket counts +edge hist)
__global__ __launch_bounds__(256) void k_setup(
        const void* W_in, const void* b_in, const void* att, const void* bconv,
        const void* Wg, const void* bg,
        const void* Wl_raw, const void* Wr_raw, const void* bl_raw, const void* br_raw,
        const void* feat_raw, const int* __restrict__ nmask,
        const int* __restrict__ e_src, const int* __restrict__ e_dst,
        float* attf, float* bcf, float* Wgf, float* bgf,
        bf16_t* __restrict__ Wt, bf16_t* __restrict__ WtS, float* __restrict__ bb,
        int* __restrict__ deg4, int* __restrict__ flag, int* __restrict__ bcount,
        bf16_t* __restrict__ h0, bf16_t* __restrict__ h) {
    __shared__ int bad;
    __shared__ float Ws[IN_DIM * HID];
    __shared__ float bs[HID];
    __shared__ int wcnt[4][4];
    int t = threadIdx.x, bid = blockIdx.x;
    if (t == 0) bad = 0;
    __syncthreads();
    {
        const bf16_t* p = (const bf16_t*)W_in;
        int mybad = 0;
        for (int i = t; i < IN_DIM * HID; i += 256) {
            float v = b2f(p[i]);
            if (v != v || fabsf(v) > 100.f) mybad = 1;
        }
        if (mybad) atomicOr(&bad, 1);
    }
    __syncthreads();
    int f = bad ? 0 : 1;
    if (bid == 0 && t == 0) *flag = f;

    if (bid < 256) {
        int i = bid * 256 + t;              // over 512*128
        int n = i >> 7, k = i & 127;
        const void* W = (n < 256) ? Wl_raw : Wr_raw;
        int nn = (n < 256) ? n : n - 256;
        float v = f ? b2f(((const bf16_t*)W)[k * 256 + nn])
                    : ((const float*)W)[k * 256 + nn];
        Wt[n * 128 + k] = f2b(v);
        if (k < 64) {
            float v2 = f ? b2f(((const bf16_t*)W)[(k + 64) * 256 + nn])
                         : ((const float*)W)[(k + 64) * 256 + nn];
            WtS[n * 64 + k] = f2b(v + v2);   // step-0 weights: x=[h0|h0]
        }
        if (k == 0) {
            const void* b = (n < 256) ? bl_raw : br_raw;
            bb[n] = f ? b2f(((const bf16_t*)b)[nn]) : ((const float*)b)[nn];
        }
    } else if (bid < 267) {
        int i = (bid - 256) * 256 + t;      // over 2592
        const void* src; float* dst; int off;
        if      (i < 256)  { src = att;   dst = attf; off = i; }
        else if (i < 512)  { src = bconv; dst = bcf;  off = i - 256; }
        else if (i < 2560) { src = Wg;    dst = Wgf;  off = i - 512; }
        else if (i < 2592) { src = bg;    dst = bgf;  off = i - 2560; }
        else return;
        dst[off] = f ? b2f(((const bf16_t*)src)[off]) : ((const float*)src)[off];
    } else if (bid < 267 + NB_NODE) {
        // per-block mask-bucket counts (deg4 zeroed by host memset)
        int nb = bid - 267;
        int i = nb * 256 + t;
        bool valid = i < NN;
        int wid = t >> 6, lane = t & 63;
        int v = 0;
        if (valid) { int m = nmask[i]; v = m < 0 ? 0 : (m > 3 ? 3 : m); }
#pragma unroll
        for (int b = 0; b < 4; b++) {
            unsigned long long mm = __ballot(valid && v == b);
            if (lane == 0) wcnt[wid][b] = __popcll(mm);
        }
        __syncthreads();
        if (t < 4)
            bcount[nb * 4 + t] = wcnt[0][t] + wcnt[1][t] + wcnt[2][t] + wcnt[3][t];
    } else if (bid < 267 + NB_NODE + EB) {
        // edge histogram: per-(dst, src-mask-bucket) degree
        int nb = bid - 267 - NB_NODE;
        int i = (nb * 256 + t) * 4;
        if (i + 3 < EE) {
            int4 dv = *(const int4*)(e_dst + i);
            int4 sv = *(const int4*)(e_src + i);
            int m0 = nmask[sv.x]; m0 = m0 < 0 ? 0 : (m0 > 3 ? 3 : m0);
            int m1 = nmask[sv.y]; m1 = m1 < 0 ? 0 : (m1 > 3 ? 3 : m1);
            int m2 = nmask[sv.z]; m2 = m2 < 0 ? 0 : (m2 > 3 ? 3 : m2);
            int m3 = nmask[sv.w]; m3 = m3 < 0 ? 0 : (m3 > 3 ? 3 : m3);
            atomicAdd(&deg4[dv.x * 4 + m0], 1);
            atomicAdd(&deg4[dv.y * 4 + m1], 1);
            atomicAdd(&deg4[dv.z * 4 + m2], 1);
            atomicAdd(&deg4[dv.w * 4 + m3], 1);
        } else {
            for (; i < EE; i++) {
                int s = e_src[i];
                int m = nmask[s]; m = m < 0 ? 0 : (m > 3 ? 3 : m);
                atomicAdd(&deg4[e_dst[i] * 4 + m], 1);
            }
        }
    } else {
        // h0: stage W_in/b_in once, then 16 groups x 4 nodes = 64 nodes/block
        for (int i = t; i < IN_DIM * HID; i += 256)
            Ws[i] = f ? b2f(((const bf16_t*)W_in)[i]) : ((const float*)W_in)[i];
        if (t < HID)
            bs[t] = f ? b2f(((const bf16_t*)b_in)[t]) : ((const float*)b_in)[t];
        __syncthreads();
        int nb = bid - (267 + NB_NODE + EB);
        int wid = t >> 6, c = t & 63;
#pragma unroll
        for (int g = 0; g < 16; g++) {
            int node = (nb * 16 + g) * 4 + wid;
            if (node >= NN) break;
            float acc = bs[c];
            if (f) {
                const short8* fr8 = (const short8*)((const bf16_t*)feat_raw
                                                    + (size_t)node * IN_DIM);
#pragma unroll
                for (int j = 0; j < 4; j++) {
                    short8 fv = fr8[j];
#pragma unroll
                    for (int k = 0; k < 8; k++)
                        acc += b2f((bf16_t)fv[k]) * Ws[(j * 8 + k) * HID + c];
                }
            } else {
                const float4* fr4 = (const float4*)((const float*)feat_raw
                                                    + (size_t)node * IN_DIM);
#pragma unroll
                for (int j = 0; j < 8; j++) {
                    float4 fv = fr4[j];
                    acc += fv.x * Ws[(j * 4 + 0) * HID + c];
                    acc += fv.y * Ws[(j * 4 + 1) * HID + c];
                    acc += fv.z * Ws[(j * 4 + 2) * HID + c];
                    acc += fv.w * Ws[(j * 4 + 3) * HID + c];
                }
            }
            bf16_t o = f2b(acc);
            h0[(size_t)node * HID + c] = o;
            h [(size_t)node * HID + c] = o;
        }
    }
}

// ---------------------------------------------------------------- single-kernel scan over deg4
__global__ __launch_bounds__(256) void k_scan(const int* __restrict__ deg4,
                                              int* __restrict__ cur4,
                                              int* __restrict__ rend4,
                                              const int* __restrict__ bcount,
                                              int* __restrict__ mbuf,
                                              int n, int nch) {
    __shared__ int sc[256];
    __shared__ int spre[256];
    __shared__ int cb[4];
    int t = threadIdx.x, bid = blockIdx.x;

    if (bid == 0) {
        if (t < 4) cb[t] = 0;
        __syncthreads();
        for (int i = t; i < NBC; i += 256) atomicAdd(&cb[i & 3], bcount[i]);
        __syncthreads();
        if (t == 0) {
            int c1 = cb[1], c2 = cb[2], c3 = cb[3];
            mbuf[7] = 0;              // order bucket 3 cursor
            mbuf[6] = c3;             // bucket 2
            mbuf[5] = c3 + c2;        // bucket 1
            mbuf[4] = c3 + c2 + c1;   // bucket 0
            mbuf[8] = c3 + c2 + c1;   // active at step 0
            mbuf[9] = c3 + c2;        // step 1
            mbuf[10] = c3;            // step 2
        }
    }

    const int4* d4 = (const int4*)deg4;   // one int4 = one node's 4 bucket degrees
    int base = bid * 1024;
    // global prefix of all nodes before this chunk
    int pre = 0;
    for (int i = t; i < base; i += 256) {
        int4 q = d4[i];
        pre += q.x + q.y + q.z + q.w;
    }
    spre[t] = pre; __syncthreads();
    for (int off = 128; off > 0; off >>= 1) {
        if (t < off) spre[t] += spre[t + off];
        __syncthreads();
    }
    int bpref = spre[0];

    int4 dd[4]; int tot[4]; int s = 0;
#pragma unroll
    for (int j = 0; j < 4; j++) {
        int i = base + t * 4 + j;
        if (i < n) dd[j] = d4[i];
        else { dd[j].x = 0; dd[j].y = 0; dd[j].z = 0; dd[j].w = 0; }
        tot[j] = dd[j].x + dd[j].y + dd[j].z + dd[j].w;
        s += tot[j];
    }
    sc[t] = s; __syncthreads();
    for (int off = 1; off < 256; off <<= 1) {
        int add = (t >= off) ? sc[t - off] : 0;
        __syncthreads();
        sc[t] += add;
        __syncthreads();
    }
    int run = sc[t] - s + bpref;
#pragma unroll
    for (int j = 0; j < 4; j++) {
        int i = base + t * 4 + j;
        if (i < n) {
            int c3 = run;                 // start of bucket 3
            int c2 = c3 + dd[j].w;        // start of bucket 2
            int c1 = c2 + dd[j].z;        // start of bucket 1
            int c0 = c1 + dd[j].y;        // start of bucket 0
            int4 cu; cu.x = c0; cu.y = c1; cu.z = c2; cu.w = c3;
            *(int4*)(cur4 + i * 4) = cu;
            int4 re; re.x = c0; re.y = c1; re.z = c2; re.w = run;  // ends + row start
            *(int4*)(rend4 + i * 4) = re;
        }
        run += tot[j];
    }
}

// ---------------------------------------------------------------- scatter: bucket-sorted CSR cols + compaction order
__global__ __launch_bounds__(256) void k_scatter_all(const int* __restrict__ src,
                                                     const int* __restrict__ dst,
                                                     int* __restrict__ cur4,
                                                     int* __restrict__ col,
                                                     const int* __restrict__ mask,
                                                     int* __restrict__ mbuf,
                                                     int* __restrict__ order) {
    int t = threadIdx.x, bid = blockIdx.x;
    int i = bid * 256 + t;
    if (i < EE) {
        int sv = src[i];
        int m = mask[sv]; m = m < 0 ? 0 : (m > 3 ? 3 : m);
        int d = dst[i];
        int pos = atomicAdd(&cur4[d * 4 + m], 1);
        col[pos] = sv;                       // bucket-sorted: no mask packing needed
    }
    if (bid < NB_NODE) {
        __shared__ int wcnt[4][4];
        __shared__ int bbase[4];
        int wid = t >> 6, lane = t & 63;
        int ni = bid * 256 + t;
        bool valid = ni < NN;
        int v = 0;
        if (valid) { int m = mask[ni]; v = m < 0 ? 0 : (m > 3 ? 3 : m); }
        int rank = 0;
#pragma unroll
        for (int b = 0; b < 4; b++) {
            unsigned long long mm = __ballot(valid && v == b);
            if (valid && v == b)
                rank = __popcll(mm & ((lane == 0) ? 0ull : (~0ull >> (64 - lane))));
            if (lane == 0) wcnt[wid][b] = __popcll(mm);
        }
        __syncthreads();
        if (t < 4) {
            int tot = wcnt[0][t] + wcnt[1][t] + wcnt[2][t] + wcnt[3][t];
            bbase[t] = atomicAdd(&mbuf[4 + t], tot);   // one atomic/bucket/block
        }
        __syncthreads();
        if (valid) {
            int wpre = 0;
            for (int ww = 0; ww < wid; ww++) wpre += wcnt[ww][v];
            order[bbase[v] + wpre + rank] = ni;
        }
    }
}

// ---------------------------------------------------------------- step-0 MFMA GEMM (K=64, pre-summed weights)
__global__ __launch_bounds__(256) void k_gemm0(const bf16_t* __restrict__ h0,
                                               const bf16_t* __restrict__ WtS,
                                               const float* __restrict__ bb,
                                               bf16_t* __restrict__ xl,
                                               bf16_t* __restrict__ xr,
                                               const int* __restrict__ order,
                                               const int* __restrict__ mbuf) {
    int count = mbuf[8];
    int mbase = blockIdx.x * 64;
    if (mbase >= count) return;

    __shared__ bf16_t smem[64 * 72 + 128 * 72];   // 27.6 KB
    bf16_t* As = smem;
    bf16_t* Bs = smem + 64 * 72;
    bf16_t* Cs = smem;                             // 64*136=8704 <= 13824

    int t = threadIdx.x;
    int nbase = blockIdx.y * 128;

    {
        int ln = t >> 2, lq = t & 3;
        int idx = mbase + ln;
        int node = (idx < count) ? order[idx] : -1;
        ulonglong2 z; z.x = 0; z.y = 0;
        ulonglong2 v0 = z, v1 = z;
        if (node >= 0) {
            v0 = *(const ulonglong2*)(h0 + (size_t)node * HID + lq * 16);
            v1 = *(const ulonglong2*)(h0 + (size_t)node * HID + lq * 16 + 8);
        }
        *(ulonglong2*)(&As[ln * 72 + lq * 16]) = v0;
        *(ulonglong2*)(&As[ln * 72 + lq * 16 + 8]) = v1;
    }
    {
        int n = t >> 1, kc = (t & 1) * 32;
        const bf16_t* srcp = WtS + (size_t)(nbase + n) * 64 + kc;
        bf16_t* dstp = &Bs[n * 72 + kc];
        *(ulonglong2*)(dstp)      = *(const ulonglong2*)(srcp);
        *(ulonglong2*)(dstp + 8)  = *(const ulonglong2*)(srcp + 8);
        *(ulonglong2*)(dstp + 16) = *(const ulonglong2*)(srcp + 16);
        *(ulonglong2*)(dstp + 24) = *(const ulonglong2*)(srcp + 24);
    }
    __syncthreads();

    int wv = t >> 6, lane = t & 63, mrow = lane & 15, quad = lane >> 4;
    floatx4 acc[8];
#pragma unroll
    for (int nf = 0; nf < 8; nf++) acc[nf] = (floatx4){0.f, 0.f, 0.f, 0.f};
#pragma unroll
    for (int kq = 0; kq < 2; kq++) {
        short8 a = *(const short8*)(&As[(wv * 16 + mrow) * 72 + kq * 32 + quad * 8]);
#pragma unroll
        for (int nf = 0; nf < 8; nf++) {
            short8 b = *(const short8*)(&Bs[(nf * 16 + mrow) * 72 + kq * 32 + quad * 8]);
            acc[nf] = __builtin_amdgcn_mfma_f32_16x16x32_bf16(a, b, acc[nf], 0, 0, 0);
        }
    }
    __syncthreads();

#pragma unroll
    for (int nf = 0; nf < 8; nf++) {
        float bv = bb[nbase + nf * 16 + mrow];
#pragma unroll
        for (int r = 0; r < 4; r++) {
            int m = wv * 16 + quad * 4 + r;
            Cs[m * 136 + nf * 16 + mrow] = f2b(acc[nf][r] + bv);
        }
    }
    __syncthreads();

    bf16_t* outp = (blockIdx.y < 2) ? xl : xr;
    int cc = (blockIdx.y & 1) * 128;
#pragma unroll
    for (int i = 0; i < 4; i++) {
        int c = t + i * 256;
        int m = c >> 4, kc = (c & 15) * 8;
        int idx = mbase + m;
        if (idx < count) {
            int node = order[idx];
            *(ulonglong2*)(outp + (size_t)node * 256 + cc + kc) =
                *(const ulonglong2*)(&Cs[m * 136 + kc]);
        }
    }
}

// ---------------------------------------------------------------- steps 1-2 MFMA GEMM (K=128)
__global__ __launch_bounds__(256) void k_gemm_mfma(const bf16_t* __restrict__ h,
                                                   const bf16_t* __restrict__ h0,
                                                   const bf16_t* __restrict__ Wt,
                                                   const float* __restrict__ bb,
                                                   bf16_t* __restrict__ xl,
                                                   bf16_t* __restrict__ xr,
                                                   const int* __restrict__ order,
                                                   const int* __restrict__ mbuf,
                                                   int step) {
    int count = mbuf[8 + step];
    int mbase = blockIdx.x * 64;
    if (mbase >= count) return;

    __shared__ bf16_t smem[64 * 136 + 128 * 136];   // 52 KB
    bf16_t* As = smem;
    bf16_t* Bs = smem + 64 * 136;
    bf16_t* Cs = smem;

    int t = threadIdx.x;
    int nbase = blockIdx.y * 128;

    {
        int ln = t >> 2, lq = t & 3;
        int idx = mbase + ln;
        int node = (idx < count) ? order[idx] : -1;
        ulonglong2 z; z.x = 0; z.y = 0;
#pragma unroll
        for (int j = 0; j < 2; j++) {
            int chunk = lq + j * 4;
            ulonglong2 vh = z, vh0 = z;
            if (node >= 0) {
                vh  = *(const ulonglong2*)(h  + (size_t)node * HID + chunk * 8);
                vh0 = *(const ulonglong2*)(h0 + (size_t)node * HID + chunk * 8);
            }
            *(ulonglong2*)(&As[ln * 136 + chunk * 8]) = vh;
            *(ulonglong2*)(&As[ln * 136 + 64 + chunk * 8]) = vh0;
        }
    }
#pragma unroll
    for (int i = 0; i < 8; i++) {
        int c = t + i * 256;
        int n = c >> 4, kc = (c & 15) * 8;
        *(ulonglong2*)(&Bs[n * 136 + kc]) =
            *(const ulonglong2*)(Wt + (size_t)(nbase + n) * 128 + kc);
    }
    __syncthreads();

    int wv = t >> 6, lane = t & 63, mrow = lane & 15, quad = lane >> 4;
    floatx4 acc[8];
#pragma unroll
    for (int nf = 0; nf < 8; nf++) acc[nf] = (floatx4){0.f, 0.f, 0.f, 0.f};
#pragma unroll
    for (int kq = 0; kq < 4; kq++) {
        short8 a = *(const short8*)(&As[(wv * 16 + mrow) * 136 + kq * 32 + quad * 8]);
#pragma unroll
        for (int nf = 0; nf < 8; nf++) {
            short8 b = *(const short8*)(&Bs[(nf * 16 + mrow) * 136 + kq * 32 + quad * 8]);
            acc[nf] = __builtin_amdgcn_mfma_f32_16x16x32_bf16(a, b, acc[nf], 0, 0, 0);
        }
    }
    __syncthreads();

#pragma unroll
    for (int nf = 0; nf < 8; nf++) {
        float bv = bb[nbase + nf * 16 + mrow];
#pragma unroll
        for (int r = 0; r < 4; r++) {
            int m = wv * 16 + quad * 4 + r;
            Cs[m * 136 + nf * 16 + mrow] = f2b(acc[nf][r] + bv);
        }
    }
    __syncthreads();

    bf16_t* outp = (blockIdx.y < 2) ? xl : xr;
    int cc = (blockIdx.y & 1) * 128;
#pragma unroll
    for (int i = 0; i < 4; i++) {
        int c = t + i * 256;
        int m = c >> 4, kc = (c & 15) * 8;
        int idx = mbase + m;
        if (idx < count) {
            int node = order[idx];
            *(ulonglong2*)(outp + (size_t)node * 256 + cc + kc) =
                *(const ulonglong2*)(&Cs[m * 136 + kc]);
        }
    }
}

// ---------------------------------------------------------------- segment softmax + aggregate (in-place bf16 h)
// TWO NODES PER WAVE: each 32-lane half owns one node; lane covers 8 channels
// (ushort8). Head h = (s>>3) occupies lanes [8h,8h+8): per-head score reduce is
// an 8-lane DPP chain (xor1,xor2,half_mirror); att index = s*8+k == h*64+c.
// Head-sum epilogue = shfl_xor 8,16 (stays within each half). Halves the issued
// instructions per node and doubles rows-in-flight per wave. Unequal pair
// degrees run to max(degA,degB) with p=0 predication for dead slots.
// col over-read past e1 stays within col[]+order[] (valid ids, contributions 0).
template<int STEP>
__global__ __launch_bounds__(256) void k_agg(bf16_t* __restrict__ h,
                                             const bf16_t* __restrict__ xl,
                                             const bf16_t* __restrict__ xr,
                                             const float* __restrict__ att,
                                             const float* __restrict__ b_conv,
                                             const int* __restrict__ rend4,
                                             const int* __restrict__ col,
                                             const int* __restrict__ order,
                                             const int* __restrict__ mbuf) {
    int count = mbuf[8 + STEP];
    int t = threadIdx.x;
    int wid = t >> 6, lane = t & 63;
    int half = lane >> 5, s = lane & 31;

    // 8 floats of att (prescaled by log2 e) and b_conv per sublane
    float4 avL = *(const float4*)(att + s * 8);
    float4 avH = *(const float4*)(att + s * 8 + 4);
    avL.x *= 1.44269504f; avL.y *= 1.44269504f; avL.z *= 1.44269504f; avL.w *= 1.44269504f;
    avH.x *= 1.44269504f; avH.y *= 1.44269504f; avH.z *= 1.44269504f; avH.w *= 1.44269504f;
    float4 bcL = *(const float4*)(b_conv + s * 8);
    float4 bcH = *(const float4*)(b_conv + s * 8 + 4);

    const int pstride = gridDim.x * 8;           // 2 nodes per wave per iteration
    for (int p0 = (blockIdx.x * 4 + wid) * 2; p0 < count; p0 += pstride) {
        int myidx = p0 + half;
        bool valid = myidx < count;
        int node = order[valid ? myidx : count - 1];

        int4 re = *(const int4*)(rend4 + node * 4);
        int e0 = re.w;
        int e1 = (STEP == 0) ? re.x : (STEP == 1) ? re.y : re.z;
        int nl = e1 - e0;
        int nother = __shfl_xor(nl, 32, 64);
        int nmax = nl > nother ? nl : nother;    // pair runs to the longer list

        short8 us  = *(const short8*)(xl + (size_t)node * 256 + s * 8);
        short8 xru = *(const short8*)(xr + (size_t)node * 256 + s * 8);
        float xr0 = b2f((bf16_t)xru[0]), xr1 = b2f((bf16_t)xru[1]);
        float xr2 = b2f((bf16_t)xru[2]), xr3 = b2f((bf16_t)xru[3]);
        float xr4 = b2f((bf16_t)xru[4]), xr5 = b2f((bf16_t)xru[5]);
        float xr6 = b2f((bf16_t)xru[6]), xr7 = b2f((bf16_t)xru[7]);

        float l = 0.f;
        float c0 = 0.f, c1 = 0.f, c2 = 0.f, c3 = 0.f;
        float c4 = 0.f, c5 = 0.f, c6 = 0.f, c7 = 0.f;

        auto body = [&](short8 xu, bool live) {
            float x0 = b2f((bf16_t)xu[0]), x1 = b2f((bf16_t)xu[1]);
            float x2 = b2f((bf16_t)xu[2]), x3 = b2f((bf16_t)xu[3]);
            float x4 = b2f((bf16_t)xu[4]), x5 = b2f((bf16_t)xu[5]);
            float x6 = b2f((bf16_t)xu[6]), x7 = b2f((bf16_t)xu[7]);
            float v0 = x0 + xr0; v0 = fmaxf(v0, 0.2f * v0);
            float v1 = x1 + xr1; v1 = fmaxf(v1, 0.2f * v1);
            float v2 = x2 + xr2; v2 = fmaxf(v2, 0.2f * v2);
            float v3 = x3 + xr3; v3 = fmaxf(v3, 0.2f * v3);
            float v4 = x4 + xr4; v4 = fmaxf(v4, 0.2f * v4);
            float v5 = x5 + xr5; v5 = fmaxf(v5, 0.2f * v5);
            float v6 = x6 + xr6; v6 = fmaxf(v6, 0.2f * v6);
            float v7 = x7 + xr7; v7 = fmaxf(v7, 0.2f * v7);
            float part = avL.x * v0 + avL.y * v1 + avL.z * v2 + avL.w * v3
                       + avH.x * v4 + avH.y * v5 + avH.z * v6 + avH.w * v7;
            part = DPP_ADD(part, 0xB1);    // xor1
            part = DPP_ADD(part, 0x4E);    // xor2
            part = DPP_ADD(part, 0x141);   // half_mirror -> 8-lane (per-head) sum
            float p = live ? exp2f(part) : 0.f;   // att prescaled: == exp(score)
            l += p;
            c0 += p * x0; c1 += p * x1; c2 += p * x2; c3 += p * x3;
            c4 += p * x4; c5 += p * x5; c6 += p * x6; c7 += p * x7;
        };

        body(us, valid);                         // implicit self-loop
        for (int j = 0; j < nmax; j += 4) {
            int e = e0 + j;
            int q0 = col[e], q1 = col[e + 1], q2 = col[e + 2], q3 = col[e + 3];
            short8 r0 = *(const short8*)(xl + (size_t)q0 * 256 + s * 8);
            short8 r1 = *(const short8*)(xl + (size_t)q1 * 256 + s * 8);
            short8 r2 = *(const short8*)(xl + (size_t)q2 * 256 + s * 8);
            short8 r3 = *(const short8*)(xl + (size_t)q3 * 256 + s * 8);
            body(r0, j + 0 < nl);
            body(r1, j + 1 < nl);
            body(r2, j + 2 < nl);
            body(r3, j + 3 < nl);
        }

        float inv = __builtin_amdgcn_rcpf(l);    // l>0 for valid (self alive)
        float t0 = c0 * inv + bcL.x, t1 = c1 * inv + bcL.y;
        float t2 = c2 * inv + bcL.z, t3 = c3 * inv + bcL.w;
        float t4 = c4 * inv + bcH.x, t5 = c5 * inv + bcH.y;
        float t6 = c6 * inv + bcH.z, t7 = c7 * inv + bcH.w;
        // sum over 4 heads: lanes s, s^8, s^16, s^24 (within each half)
        t0 += __shfl_xor(t0, 8, 64); t0 += __shfl_xor(t0, 16, 64);
        t1 += __shfl_xor(t1, 8, 64); t1 += __shfl_xor(t1, 16, 64);
        t2 += __shfl_xor(t2, 8, 64); t2 += __shfl_xor(t2, 16, 64);
        t3 += __shfl_xor(t3, 8, 64); t3 += __shfl_xor(t3, 16, 64);
        t4 += __shfl_xor(t4, 8, 64); t4 += __shfl_xor(t4, 16, 64);
        t5 += __shfl_xor(t5, 8, 64); t5 += __shfl_xor(t5, 16, 64);
        t6 += __shfl_xor(t6, 8, 64); t6 += __shfl_xor(t6, 16, 64);
        t7 += __shfl_xor(t7, 8, 64); t7 += __shfl_xor(t7, 16, 64);
        if (valid && s < 8) {
            short8 o;
            o[0] = (short)f2b(tanhf(t0)); o[1] = (short)f2b(tanhf(t1));
            o[2] = (short)f2b(tanhf(t2)); o[3] = (short)f2b(tanhf(t3));
            o[4] = (short)f2b(tanhf(t4)); o[5] = (short)f2b(tanhf(t5));
            o[6] = (short)f2b(tanhf(t6)); o[7] = (short)f2b(tanhf(t7));
            *(short8*)(h + (size_t)node * HID + s * 8) = o;
        }
    }
}

// ---------------------------------------------------------------- out = (h @ Wg + bg) * (cs>0), 32 nodes/block
__global__ __launch_bounds__(256) void k_out(const bf16_t* __restrict__ h,
                                             const float* __restrict__ Wg,
                                             const float* __restrict__ bg,
                                             const int* __restrict__ cs,
                                             void* __restrict__ out,
                                             const int* __restrict__ flag) {
    __shared__ float Ws[HID * OUTD];
    __shared__ float bs[OUTD];
    int t = threadIdx.x;
    for (int i = t; i < HID * OUTD; i += 256) Ws[i] = Wg[i];
    if (t < OUTD) bs[t] = bg[t];
    __syncthreads();
    int g0 = t >> 5, c = t & 31;
    int fl = *flag;
#pragma unroll
    for (int g = 0; g < 4; g++) {
        int node = blockIdx.x * 32 + g * 8 + g0;
        if (node >= NN) break;
        float res = 0.f;
        if (cs[node] > 0) {
            const short8* hr8 = (const short8*)(h + (size_t)node * HID);
            float acc = bs[c];
#pragma unroll
            for (int j = 0; j < 8; j++) {
                short8 hv = hr8[j];
#pragma unroll
                for (int k = 0; k < 8; k++)
                    acc += b2f((bf16_t)hv[k]) * Ws[(j * 8 + k) * OUTD + c];
            }
            res = acc;
        }
        size_t idx = (size_t)node * OUTD + c;
        if (fl) ((bf16_t*)out)[idx] = f2b(res);
        else    ((float*)out)[idx]  = res;
    }
}

// ---------------------------------------------------------------- host
static inline size_t alignup(size_t x) { return (x + 255) & ~(size_t)255; }

extern "C" void kernel_launch(void* const* d_in, const int* in_sizes, int n_in,
                              void* d_out, int out_size, void* d_ws, size_t ws_size,
                              hipStream_t stream) {
    const void* feat_raw  = d_in[0];
    const void* W_in_raw  = d_in[1];
    const void* b_in_raw  = d_in[2];
    const void* Wl_raw    = d_in[3];
    const void* bl_raw    = d_in[4];
    const void* Wr_raw    = d_in[5];
    const void* br_raw    = d_in[6];
    const void* att_raw   = d_in[7];
    const void* bconv_raw = d_in[8];
    const void* Wg_raw    = d_in[9];
    const void* bg_raw    = d_in[10];
    const int* edge       = (const int*)d_in[11];    // [2][EE]: src row, dst row
    const int* nmask      = (const int*)d_in[12];
    const int* cstate     = (const int*)d_in[13];

    const int* e_src = edge;
    const int* e_dst = edge + EE;

    const size_t SZ_HB   = alignup((size_t)NN * HID * sizeof(bf16_t));
    const size_t SZ_X    = alignup((size_t)NN * 256 * sizeof(bf16_t));
    const size_t SZ_I4   = alignup((size_t)NN * 4 * sizeof(int));   // deg4/cur4/rend4
    const size_t SZ_I    = alignup((size_t)NN * sizeof(int));
    const size_t SZ_COL  = alignup((size_t)EE * sizeof(int));
    const int nch = (NN + 1023) / 1024;
    const size_t SZ_BC   = alignup((size_t)NBC * sizeof(int));
    const size_t SZ_WT   = alignup((size_t)512 * 128 * sizeof(bf16_t));
    const size_t SZ_WTS  = alignup((size_t)512 * 64 * sizeof(bf16_t));
    const size_t SZ_B    = alignup(512 * sizeof(float));
    const size_t SZ_WG   = alignup((size_t)HID * OUTD * sizeof(float));

    char* w = (char*)d_ws;
    bf16_t* h0   = (bf16_t*)w; w += SZ_HB;
    bf16_t* h    = (bf16_t*)w; w += SZ_HB;
    bf16_t* xl   = (bf16_t*)w; w += SZ_X;
    bf16_t* xr   = (bf16_t*)w; w += SZ_X;
    int* deg4    = (int*)w;    w += SZ_I4;
    int* mbuf    = (int*)w;    w += 256;     // adjacent to deg4: one memset covers both
    int* cur4    = (int*)w;    w += SZ_I4;
    int* rend4   = (int*)w;    w += SZ_I4;
    int* colA    = (int*)w;    w += SZ_COL;  // k_agg may over-read a little into order[]
    int* order   = (int*)w;    w += SZ_I;
    int* bcount  = (int*)w;    w += SZ_BC;
    bf16_t* Wt   = (bf16_t*)w; w += SZ_WT;
    bf16_t* WtS  = (bf16_t*)w; w += SZ_WTS;
    float* bb    = (float*)w;  w += SZ_B;
    float* attf  = (float*)w;  w += SZ_B;
    float* bcf   = (float*)w;  w += SZ_B;
    float* Wgf   = (float*)w;  w += SZ_WG;
    float* bgf   = (float*)w;  w += SZ_B;
    int* flag    = (int*)w;    w += 256;
    if ((size_t)(w - (char*)d_ws) > ws_size) return;

    // ---- zero deg4 + mbuf in one async memset (they are adjacent)
    hipMemsetAsync(deg4, 0, SZ_I4 + 256, stream);

    // ---- fused setup: flag + weights + bucket counts + edge hist + h0
    k_setup<<<267 + NB_NODE + EB + H0_BLOCKS, 256, 0, stream>>>(
        W_in_raw, b_in_raw, att_raw, bconv_raw, Wg_raw, bg_raw,
        Wl_raw, Wr_raw, bl_raw, br_raw, feat_raw, nmask, e_src, e_dst,
        attf, bcf, Wgf, bgf, Wt, WtS, bb, deg4, flag, bcount, h0, h);

    // ---- CSR (bucket-sorted) + compaction
    k_scan<<<nch, 256, 0, stream>>>(deg4, cur4, rend4, bcount, mbuf, NN, nch);
    k_scatter_all<<<(EE + 255) / 256, 256, 0, stream>>>(e_src, e_dst, cur4, colA,
                                                        nmask, mbuf, order);

    // ---- step 0: K=64 gemm with pre-summed weights (h==h0), then agg
    k_gemm0<<<dim3((NN + 63) / 64, 4), 256, 0, stream>>>(h0, WtS, bb, xl, xr, order, mbuf);
    k_agg<0><<<2048, 256, 0, stream>>>(h, xl, xr, attf, bcf, rend4, colA, order, mbuf);

    // ---- steps 1,2: K=128 gemm + agg
    k_gemm_mfma<<<dim3((NN + 63) / 64, 4), 256, 0, stream>>>(h, h0, Wt, bb, xl, xr,
                                                             order, mbuf, 1);
    k_agg<1><<<2048, 256, 0, stream>>>(h, xl, xr, attf, bcf, rend4, colA, order, mbuf);
    k_gemm_mfma<<<dim3((NN + 63) / 64, 4), 256, 0, stream>>>(h, h0, Wt, bb, xl, xr,
                                                             order, mbuf, 2);
    k_agg<2><<<2048, 256, 0, stream>>>(h, xl, xr, attf, bcf, rend4, colA, order, mbuf);

    // ---- epilogue
    k_out<<<(NN + 31) / 32, 256, 0, stream>>>(h, Wgf, bgf, cstate, d_out, flag);
}

// Round 8
// 274.009 us; speedup vs baseline: 1.4099x; 1.0112x over previous
//
#include <hip/hip_runtime.h>
#include <hip/hip_bf16.h>

// Problem constants (from reference)
#define NN      50000
#define EE      200000
#define IN_DIM  32
#define HID     64
#define HEADS   4
#define OUTD    32
#define TSTEPS  3

typedef unsigned short bf16_t;
typedef __attribute__((ext_vector_type(8))) short  short8;
typedef __attribute__((ext_vector_type(4))) float  floatx4;

__device__ __forceinline__ float b2f(bf16_t u) {
    union { unsigned int i; float f; } v; v.i = ((unsigned int)u) << 16; return v.f;
}
__device__ __forceinline__ bf16_t f2b(float f) {
    union { float f; unsigned int i; } v; v.f = f;
    unsigned int r = v.i + 0x7FFF + ((v.i >> 16) & 1);   // RNE
    return (bf16_t)(r >> 16);
}

// DPP-based add of a lane-permuted copy (all lanes valid, bound_ctrl=1).
// 0xB1=quad_perm[1,0,3,2](xor1), 0x4E=quad_perm[2,3,0,1](xor2),
// 0x141=row_half_mirror. Chain of 3 = sum over each 8-lane group.
#define DPP_ADD(x, ctrl) ((x) + __int_as_float(                                 \
        __builtin_amdgcn_update_dpp(0, __float_as_int(x), (ctrl), 0xF, 0xF, true)))

#define H0_BLOCKS ((NN + 63) / 64)   // h0 section: 64 nodes/block
#define NB_NODE   ((NN + 255) / 256) // 196 blocks covering node range
#define NBC       (NB_NODE * 4)      // bcount entries
#define EB        ((EE + 1023) / 1024) // edge-hist blocks (4 edges/thread)
#define PB_COL    ((EE + 1023) / 1024) // pack: col-remap blocks
#define PB_HP     ((NN + 63) / 64)     // pack: hp-fill blocks (64 nodes/block)

// ---------------------------------------------------------------- fused setup (+h0 +bucket counts +edge hist)
__global__ __launch_bounds__(256) void k_setup(
        const void* W_in, const void* b_in, const void* att, const void* bconv,
        const void* Wg, const void* bg,
        const void* Wl_raw, const void* Wr_raw, const void* bl_raw, const void* br_raw,
        const void* feat_raw, const int* __restrict__ nmask,
        const int* __restrict__ e_src, const int* __restrict__ e_dst,
        float* attf, float* bcf, float* Wgf, float* bgf,
        bf16_t* __restrict__ Wt, bf16_t* __restrict__ WtS, float* __restrict__ bb,
        int* __restrict__ deg4, int* __restrict__ flag, int* __restrict__ bcount,
        bf16_t* __restrict__ h0) {
    __shared__ int bad;
    __shared__ float Ws[IN_DIM * HID];
    __shared__ float bs[HID];
    __shared__ int wcnt[4][4];
    int t = threadIdx.x, bid = blockIdx.x;
    if (t == 0) bad = 0;
    __syncthreads();
    {
        const bf16_t* p = (const bf16_t*)W_in;
        int mybad = 0;
        for (int i = t; i < IN_DIM * HID; i += 256) {
            float v = b2f(p[i]);
            if (v != v || fabsf(v) > 100.f) mybad = 1;
        }
        if (mybad) atomicOr(&bad, 1);
    }
    __syncthreads();
    int f = bad ? 0 : 1;
    if (bid == 0 && t == 0) *flag = f;

    if (bid < 256) {
        int i = bid * 256 + t;              // over 512*128
        int n = i >> 7, k = i & 127;
        const void* W = (n < 256) ? Wl_raw : Wr_raw;
        int nn = (n < 256) ? n : n - 256;
        float v = f ? b2f(((const bf16_t*)W)[k * 256 + nn])
                    : ((const float*)W)[k * 256 + nn];
        Wt[n * 128 + k] = f2b(v);
        if (k < 64) {
            float v2 = f ? b2f(((const bf16_t*)W)[(k + 64) * 256 + nn])
                         : ((const float*)W)[(k + 64) * 256 + nn];
            WtS[n * 64 + k] = f2b(v + v2);   // step-0 weights: x=[h0|h0]
        }
        if (k == 0) {
            const void* b = (n < 256) ? bl_raw : br_raw;
            bb[n] = f ? b2f(((const bf16_t*)b)[nn]) : ((const float*)b)[nn];
        }
    } else if (bid < 267) {
        int i = (bid - 256) * 256 + t;      // over 2592
        const void* src; float* dst; int off;
        if      (i < 256)  { src = att;   dst = attf; off = i; }
        else if (i < 512)  { src = bconv; dst = bcf;  off = i - 256; }
        else if (i < 2560) { src = Wg;    dst = Wgf;  off = i - 512; }
        else if (i < 2592) { src = bg;    dst = bgf;  off = i - 2560; }
        else return;
        dst[off] = f ? b2f(((const bf16_t*)src)[off]) : ((const float*)src)[off];
    } else if (bid < 267 + NB_NODE) {
        // per-block mask-bucket counts (deg4 zeroed by host memset)
        int nb = bid - 267;
        int i = nb * 256 + t;
        bool valid = i < NN;
        int wid = t >> 6, lane = t & 63;
        int v = 0;
        if (valid) { int m = nmask[i]; v = m < 0 ? 0 : (m > 3 ? 3 : m); }
#pragma unroll
        for (int b = 0; b < 4; b++) {
            unsigned long long mm = __ballot(valid && v == b);
            if (lane == 0) wcnt[wid][b] = __popcll(mm);
        }
        __syncthreads();
        if (t < 4)
            bcount[nb * 4 + t] = wcnt[0][t] + wcnt[1][t] + wcnt[2][t] + wcnt[3][t];
    } else if (bid < 267 + NB_NODE + EB) {
        // edge histogram: per-(dst, src-mask-bucket) degree
        int nb = bid - 267 - NB_NODE;
        int i = (nb * 256 + t) * 4;
        if (i + 3 < EE) {
            int4 dv = *(const int4*)(e_dst + i);
            int4 sv = *(const int4*)(e_src + i);
            int m0 = nmask[sv.x]; m0 = m0 < 0 ? 0 : (m0 > 3 ? 3 : m0);
            int m1 = nmask[sv.y]; m1 = m1 < 0 ? 0 : (m1 > 3 ? 3 : m1);
            int m2 = nmask[sv.z]; m2 = m2 < 0 ? 0 : (m2 > 3 ? 3 : m2);
            int m3 = nmask[sv.w]; m3 = m3 < 0 ? 0 : (m3 > 3 ? 3 : m3);
            atomicAdd(&deg4[dv.x * 4 + m0], 1);
            atomicAdd(&deg4[dv.y * 4 + m1], 1);
            atomicAdd(&deg4[dv.z * 4 + m2], 1);
            atomicAdd(&deg4[dv.w * 4 + m3], 1);
        } else {
            for (; i < EE; i++) {
                int s = e_src[i];
                int m = nmask[s]; m = m < 0 ? 0 : (m > 3 ? 3 : m);
                atomicAdd(&deg4[e_dst[i] * 4 + m], 1);
            }
        }
    } else {
        // h0: stage W_in/b_in once, then 16 groups x 4 nodes = 64 nodes/block
        for (int i = t; i < IN_DIM * HID; i += 256)
            Ws[i] = f ? b2f(((const bf16_t*)W_in)[i]) : ((const float*)W_in)[i];
        if (t < HID)
            bs[t] = f ? b2f(((const bf16_t*)b_in)[t]) : ((const float*)b_in)[t];
        __syncthreads();
        int nb = bid - (267 + NB_NODE + EB);
        int wid = t >> 6, c = t & 63;
#pragma unroll
        for (int g = 0; g < 16; g++) {
            int node = (nb * 16 + g) * 4 + wid;
            if (node >= NN) break;
            float acc = bs[c];
            if (f) {
                const short8* fr8 = (const short8*)((const bf16_t*)feat_raw
                                                    + (size_t)node * IN_DIM);
#pragma unroll
                for (int j = 0; j < 4; j++) {
                    short8 fv = fr8[j];
#pragma unroll
                    for (int k = 0; k < 8; k++)
                        acc += b2f((bf16_t)fv[k]) * Ws[(j * 8 + k) * HID + c];
                }
            } else {
                const float4* fr4 = (const float4*)((const float*)feat_raw
                                                    + (size_t)node * IN_DIM);
#pragma unroll
                for (int j = 0; j < 8; j++) {
                    float4 fv = fr4[j];
                    acc += fv.x * Ws[(j * 4 + 0) * HID + c];
                    acc += fv.y * Ws[(j * 4 + 1) * HID + c];
                    acc += fv.z * Ws[(j * 4 + 2) * HID + c];
                    acc += fv.w * Ws[(j * 4 + 3) * HID + c];
                }
            }
            h0[(size_t)node * HID + c] = f2b(acc);
        }
    }
}

// ---------------------------------------------------------------- single-kernel scan over deg4
__global__ __launch_bounds__(256) void k_scan(const int* __restrict__ deg4,
                                              int* __restrict__ cur4,
                                              int* __restrict__ rend4,
                                              const int* __restrict__ bcount,
                                              int* __restrict__ mbuf,
                                              int n, int nch) {
    __shared__ int sc[256];
    __shared__ int spre[256];
    __shared__ int cb[4];
    int t = threadIdx.x, bid = blockIdx.x;

    if (bid == 0) {
        if (t < 4) cb[t] = 0;
        __syncthreads();
        for (int i = t; i < NBC; i += 256) atomicAdd(&cb[i & 3], bcount[i]);
        __syncthreads();
        if (t == 0) {
            int c1 = cb[1], c2 = cb[2], c3 = cb[3];
            mbuf[7] = 0;              // order bucket 3 cursor
            mbuf[6] = c3;             // bucket 2
            mbuf[5] = c3 + c2;        // bucket 1
            mbuf[4] = c3 + c2 + c1;   // bucket 0
            mbuf[8] = c3 + c2 + c1;   // active at step 0
            mbuf[9] = c3 + c2;        // step 1
            mbuf[10] = c3;            // step 2
        }
    }

    const int4* d4 = (const int4*)deg4;   // one int4 = one node's 4 bucket degrees
    int base = bid * 1024;
    // global prefix of all nodes before this chunk
    int pre = 0;
    for (int i = t; i < base; i += 256) {
        int4 q = d4[i];
        pre += q.x + q.y + q.z + q.w;
    }
    spre[t] = pre; __syncthreads();
    for (int off = 128; off > 0; off >>= 1) {
        if (t < off) spre[t] += spre[t + off];
        __syncthreads();
    }
    int bpref = spre[0];

    int4 dd[4]; int tot[4]; int s = 0;
#pragma unroll
    for (int j = 0; j < 4; j++) {
        int i = base + t * 4 + j;
        if (i < n) dd[j] = d4[i];
        else { dd[j].x = 0; dd[j].y = 0; dd[j].z = 0; dd[j].w = 0; }
        tot[j] = dd[j].x + dd[j].y + dd[j].z + dd[j].w;
        s += tot[j];
    }
    sc[t] = s; __syncthreads();
    for (int off = 1; off < 256; off <<= 1) {
        int add = (t >= off) ? sc[t - off] : 0;
        __syncthreads();
        sc[t] += add;
        __syncthreads();
    }
    int run = sc[t] - s + bpref;
#pragma unroll
    for (int j = 0; j < 4; j++) {
        int i = base + t * 4 + j;
        if (i < n) {
            int c3 = run;                 // start of bucket 3
            int c2 = c3 + dd[j].w;        // start of bucket 2
            int c1 = c2 + dd[j].z;        // start of bucket 1
            int c0 = c1 + dd[j].y;        // start of bucket 0
            int4 cu; cu.x = c0; cu.y = c1; cu.z = c2; cu.w = c3;
            *(int4*)(cur4 + i * 4) = cu;
            int4 re; re.x = c0; re.y = c1; re.z = c2; re.w = run;  // ends + row start
            *(int4*)(rend4 + i * 4) = re;
        }
        run += tot[j];
    }
}

// ---------------------------------------------------------------- scatter: bucket-sorted CSR cols + compaction order
// Also emits rank[node] (inverse permutation) and rank-packed re_p[idx].
__global__ __launch_bounds__(256) void k_scatter_all(const int* __restrict__ src,
                                                     const int* __restrict__ dst,
                                                     int* __restrict__ cur4,
                                                     int* __restrict__ col,
                                                     const int* __restrict__ mask,
                                                     const int* __restrict__ rend4,
                                                     int* __restrict__ mbuf,
                                                     int* __restrict__ order,
                                                     int* __restrict__ rank,
                                                     int* __restrict__ re_p) {
    int t = threadIdx.x, bid = blockIdx.x;
    int i = bid * 256 + t;
    if (i < EE) {
        int sv = src[i];
        int m = mask[sv]; m = m < 0 ? 0 : (m > 3 ? 3 : m);
        int d = dst[i];
        int pos = atomicAdd(&cur4[d * 4 + m], 1);
        col[pos] = sv;                       // node ids; remapped to ranks in k_pack
    }
    if (bid < NB_NODE) {
        __shared__ int wcnt[4][4];
        __shared__ int bbase[4];
        int wid = t >> 6, lane = t & 63;
        int ni = bid * 256 + t;
        bool valid = ni < NN;
        int v = 0;
        if (valid) { int m = mask[ni]; v = m < 0 ? 0 : (m > 3 ? 3 : m); }
        int rk = 0;
#pragma unroll
        for (int b = 0; b < 4; b++) {
            unsigned long long mm = __ballot(valid && v == b);
            if (valid && v == b)
                rk = __popcll(mm & ((lane == 0) ? 0ull : (~0ull >> (64 - lane))));
            if (lane == 0) wcnt[wid][b] = __popcll(mm);
        }
        __syncthreads();
        if (t < 4) {
            int tot = wcnt[0][t] + wcnt[1][t] + wcnt[2][t] + wcnt[3][t];
            bbase[t] = atomicAdd(&mbuf[4 + t], tot);   // one atomic/bucket/block
        }
        __syncthreads();
        if (valid) {
            int wpre = 0;
            for (int ww = 0; ww < wid; ww++) wpre += wcnt[ww][v];
            int pos = bbase[v] + wpre + rk;
            order[pos] = ni;
            rank[ni] = pos;
            *(int4*)(re_p + pos * 4) = *(const int4*)(rend4 + ni * 4);
        }
    }
}

// ---------------------------------------------------------------- pack: col node-id -> rank, hp[idx] = [h0|h0] in order space
__global__ __launch_bounds__(256) void k_pack(int* __restrict__ col,
                                              const int* __restrict__ rank,
                                              const int* __restrict__ order,
                                              const bf16_t* __restrict__ h0,
                                              bf16_t* __restrict__ hp) {
    int t = threadIdx.x, bid = blockIdx.x;
    if (bid < PB_COL) {
        int i = (bid * 256 + t) * 4;
        if (i + 3 < EE) {
            int4 c = *(const int4*)(col + i);
            c.x = rank[c.x]; c.y = rank[c.y]; c.z = rank[c.z]; c.w = rank[c.w];
            *(int4*)(col + i) = c;
        } else {
            for (; i < EE; i++) col[i] = rank[col[i]];
        }
    } else {
        int nb = bid - PB_COL;
        int ln = t >> 2, lq = t & 3;
        int idx = nb * 64 + ln;
        if (idx >= NN) return;
        int node = order[idx];
        ulonglong2 v0 = *(const ulonglong2*)(h0 + (size_t)node * HID + lq * 16);
        ulonglong2 v1 = *(const ulonglong2*)(h0 + (size_t)node * HID + lq * 16 + 8);
        bf16_t* dstp = hp + (size_t)idx * 128;
        *(ulonglong2*)(dstp + lq * 16)       = v0;
        *(ulonglong2*)(dstp + lq * 16 + 8)   = v1;
        *(ulonglong2*)(dstp + 64 + lq * 16)  = v0;
        *(ulonglong2*)(dstp + 64 + lq * 16 + 8) = v1;
    }
}

// ---------------------------------------------------------------- step-0 MFMA GEMM (K=64, pre-summed weights)
// A rows stream from packed hp (h half); C writes contiguous at idx.
__global__ __launch_bounds__(256) void k_gemm0(const bf16_t* __restrict__ hp,
                                               const bf16_t* __restrict__ WtS,
                                               const float* __restrict__ bb,
                                               bf16_t* __restrict__ xl,
                                               bf16_t* __restrict__ xr,
                                               const int* __restrict__ mbuf) {
    int count = mbuf[8];
    int mbase = blockIdx.x * 64;
    if (mbase >= count) return;

    __shared__ bf16_t smem[64 * 72 + 128 * 72];   // 27.6 KB
    bf16_t* As = smem;
    bf16_t* Bs = smem + 64 * 72;
    bf16_t* Cs = smem;                             // 64*136=8704 <= 13824

    int t = threadIdx.x;
    int nbase = blockIdx.y * 128;

    {
        int ln = t >> 2, lq = t & 3;
        int idx = mbase + ln;
        ulonglong2 z; z.x = 0; z.y = 0;
        ulonglong2 v0 = z, v1 = z;
        if (idx < count) {
            v0 = *(const ulonglong2*)(hp + (size_t)idx * 128 + lq * 16);
            v1 = *(const ulonglong2*)(hp + (size_t)idx * 128 + lq * 16 + 8);
        }
        *(ulonglong2*)(&As[ln * 72 + lq * 16]) = v0;
        *(ulonglong2*)(&As[ln * 72 + lq * 16 + 8]) = v1;
    }
    {
        int n = t >> 1, kc = (t & 1) * 32;
        const bf16_t* srcp = WtS + (size_t)(nbase + n) * 64 + kc;
        bf16_t* dstp = &Bs[n * 72 + kc];
        *(ulonglong2*)(dstp)      = *(const ulonglong2*)(srcp);
        *(ulonglong2*)(dstp + 8)  = *(const ulonglong2*)(srcp + 8);
        *(ulonglong2*)(dstp + 16) = *(const ulonglong2*)(srcp + 16);
        *(ulonglong2*)(dstp + 24) = *(const ulonglong2*)(srcp + 24);
    }
    __syncthreads();

    int wv = t >> 6, lane = t & 63, mrow = lane & 15, quad = lane >> 4;
    floatx4 acc[8];
#pragma unroll
    for (int nf = 0; nf < 8; nf++) acc[nf] = (floatx4){0.f, 0.f, 0.f, 0.f};
#pragma unroll
    for (int kq = 0; kq < 2; kq++) {
        short8 a = *(const short8*)(&As[(wv * 16 + mrow) * 72 + kq * 32 + quad * 8]);
#pragma unroll
        for (int nf = 0; nf < 8; nf++) {
            short8 b = *(const short8*)(&Bs[(nf * 16 + mrow) * 72 + kq * 32 + quad * 8]);
            acc[nf] = __builtin_amdgcn_mfma_f32_16x16x32_bf16(a, b, acc[nf], 0, 0, 0);
        }
    }
    __syncthreads();

#pragma unroll
    for (int nf = 0; nf < 8; nf++) {
        float bv = bb[nbase + nf * 16 + mrow];
#pragma unroll
        for (int r = 0; r < 4; r++) {
            int m = wv * 16 + quad * 4 + r;
            Cs[m * 136 + nf * 16 + mrow] = f2b(acc[nf][r] + bv);
        }
    }
    __syncthreads();

    bf16_t* outp = (blockIdx.y < 2) ? xl : xr;
    int cc = (blockIdx.y & 1) * 128;
#pragma unroll
    for (int i = 0; i < 4; i++) {
        int c = t + i * 256;
        int m = c >> 4, kc = (c & 15) * 8;
        int idx = mbase + m;
        if (idx < count) {
            *(ulonglong2*)(outp + (size_t)idx * 256 + cc + kc) =
                *(const ulonglong2*)(&Cs[m * 136 + kc]);
        }
    }
}

// ---------------------------------------------------------------- steps 1-2 MFMA GEMM (K=128)
// A rows stream from packed hp ([h|h0] contiguous); C writes contiguous at idx.
__global__ __launch_bounds__(256) void k_gemm_mfma(const bf16_t* __restrict__ hp,
                                                   const bf16_t* __restrict__ Wt,
                                                   const float* __restrict__ bb,
                                                   bf16_t* __restrict__ xl,
                                                   bf16_t* __restrict__ xr,
                                                   const int* __restrict__ mbuf,
                                                   int step) {
    int count = mbuf[8 + step];
    int mbase = blockIdx.x * 64;
    if (mbase >= count) return;

    __shared__ bf16_t smem[64 * 136 + 128 * 136];   // 52 KB
    bf16_t* As = smem;
    bf16_t* Bs = smem + 64 * 136;
    bf16_t* Cs = smem;

    int t = threadIdx.x;
    int nbase = blockIdx.y * 128;

    {
        int ln = t >> 2, lq = t & 3;
        int idx = mbase + ln;
        ulonglong2 z; z.x = 0; z.y = 0;
#pragma unroll
        for (int j = 0; j < 2; j++) {
            ulonglong2 v0 = z, v1 = z;
            if (idx < count) {
                v0 = *(const ulonglong2*)(hp + (size_t)idx * 128 + lq * 32 + j * 16);
                v1 = *(const ulonglong2*)(hp + (size_t)idx * 128 + lq * 32 + j * 16 + 8);
            }
            *(ulonglong2*)(&As[ln * 136 + lq * 32 + j * 16]) = v0;
            *(ulonglong2*)(&As[ln * 136 + lq * 32 + j * 16 + 8]) = v1;
        }
    }
#pragma unroll
    for (int i = 0; i < 8; i++) {
        int c = t + i * 256;
        int n = c >> 4, kc = (c & 15) * 8;
        *(ulonglong2*)(&Bs[n * 136 + kc]) =
            *(const ulonglong2*)(Wt + (size_t)(nbase + n) * 128 + kc);
    }
    __syncthreads();

    int wv = t >> 6, lane = t & 63, mrow = lane & 15, quad = lane >> 4;
    floatx4 acc[8];
#pragma unroll
    for (int nf = 0; nf < 8; nf++) acc[nf] = (floatx4){0.f, 0.f, 0.f, 0.f};
#pragma unroll
    for (int kq = 0; kq < 4; kq++) {
        short8 a = *(const short8*)(&As[(wv * 16 + mrow) * 136 + kq * 32 + quad * 8]);
#pragma unroll
        for (int nf = 0; nf < 8; nf++) {
            short8 b = *(const short8*)(&Bs[(nf * 16 + mrow) * 136 + kq * 32 + quad * 8]);
            acc[nf] = __builtin_amdgcn_mfma_f32_16x16x32_bf16(a, b, acc[nf], 0, 0, 0);
        }
    }
    __syncthreads();

#pragma unroll
    for (int nf = 0; nf < 8; nf++) {
        float bv = bb[nbase + nf * 16 + mrow];
#pragma unroll
        for (int r = 0; r < 4; r++) {
            int m = wv * 16 + quad * 4 + r;
            Cs[m * 136 + nf * 16 + mrow] = f2b(acc[nf][r] + bv);
        }
    }
    __syncthreads();

    bf16_t* outp = (blockIdx.y < 2) ? xl : xr;
    int cc = (blockIdx.y & 1) * 128;
#pragma unroll
    for (int i = 0; i < 4; i++) {
        int c = t + i * 256;
        int m = c >> 4, kc = (c & 15) * 8;
        int idx = mbase + m;
        if (idx < count) {
            *(ulonglong2*)(outp + (size_t)idx * 256 + cc + kc) =
                *(const ulonglong2*)(&Cs[m * 136 + kc]);
        }
    }
}

// ---------------------------------------------------------------- segment softmax + aggregate
// Order-space everywhere: self/xr/re_p stream at idx, col holds ranks so the
// only gathers left are neighbor xl rows. Output h written into hp[idx][0:64].
// TWO NODES PER WAVE (32-lane halves, ushort8/lane, 8-lane DPP head reduce).
template<int STEP>
__global__ __launch_bounds__(256) void k_agg(bf16_t* __restrict__ hp,
                                             const bf16_t* __restrict__ xl,
                                             const bf16_t* __restrict__ xr,
                                             const float* __restrict__ att,
                                             const float* __restrict__ b_conv,
                                             const int* __restrict__ re_p,
                                             const int* __restrict__ col,
                                             const int* __restrict__ mbuf) {
    int count = mbuf[8 + STEP];
    int t = threadIdx.x;
    int wid = t >> 6, lane = t & 63;
    int half = lane >> 5, s = lane & 31;

    float4 avL = *(const float4*)(att + s * 8);
    float4 avH = *(const float4*)(att + s * 8 + 4);
    avL.x *= 1.44269504f; avL.y *= 1.44269504f; avL.z *= 1.44269504f; avL.w *= 1.44269504f;
    avH.x *= 1.44269504f; avH.y *= 1.44269504f; avH.z *= 1.44269504f; avH.w *= 1.44269504f;
    float4 bcL = *(const float4*)(b_conv + s * 8);
    float4 bcH = *(const float4*)(b_conv + s * 8 + 4);

    const int pstride = gridDim.x * 8;           // 2 nodes per wave per iteration
    for (int p0 = (blockIdx.x * 4 + wid) * 2; p0 < count; p0 += pstride) {
        int myidx = p0 + half;
        bool valid = myidx < count;
        int ridx = valid ? myidx : count - 1;

        int4 re = *(const int4*)(re_p + ridx * 4);
        int e0 = re.w;
        int e1 = (STEP == 0) ? re.x : (STEP == 1) ? re.y : re.z;
        int nl = e1 - e0;
        int nother = __shfl_xor(nl, 32, 64);
        int nmax = nl > nother ? nl : nother;    // pair runs to the longer list

        short8 us  = *(const short8*)(xl + (size_t)ridx * 256 + s * 8);
        short8 xru = *(const short8*)(xr + (size_t)ridx * 256 + s * 8);
        float xr0 = b2f((bf16_t)xru[0]), xr1 = b2f((bf16_t)xru[1]);
        float xr2 = b2f((bf16_t)xru[2]), xr3 = b2f((bf16_t)xru[3]);
        float xr4 = b2f((bf16_t)xru[4]), xr5 = b2f((bf16_t)xru[5]);
        float xr6 = b2f((bf16_t)xru[6]), xr7 = b2f((bf16_t)xru[7]);

        float l = 0.f;
        float c0 = 0.f, c1 = 0.f, c2 = 0.f, c3 = 0.f;
        float c4 = 0.f, c5 = 0.f, c6 = 0.f, c7 = 0.f;

        auto body = [&](short8 xu, bool live) {
            float x0 = b2f((bf16_t)xu[0]), x1 = b2f((bf16_t)xu[1]);
            float x2 = b2f((bf16_t)xu[2]), x3 = b2f((bf16_t)xu[3]);
            float x4 = b2f((bf16_t)xu[4]), x5 = b2f((bf16_t)xu[5]);
            float x6 = b2f((bf16_t)xu[6]), x7 = b2f((bf16_t)xu[7]);
            float v0 = x0 + xr0; v0 = fmaxf(v0, 0.2f * v0);
            float v1 = x1 + xr1; v1 = fmaxf(v1, 0.2f * v1);
            float v2 = x2 + xr2; v2 = fmaxf(v2, 0.2f * v2);
            float v3 = x3 + xr3; v3 = fmaxf(v3, 0.2f * v3);
            float v4 = x4 + xr4; v4 = fmaxf(v4, 0.2f * v4);
            float v5 = x5 + xr5; v5 = fmaxf(v5, 0.2f * v5);
            float v6 = x6 + xr6; v6 = fmaxf(v6, 0.2f * v6);
            float v7 = x7 + xr7; v7 = fmaxf(v7, 0.2f * v7);
            float part = avL.x * v0 + avL.y * v1 + avL.z * v2 + avL.w * v3
                       + avH.x * v4 + avH.y * v5 + avH.z * v6 + avH.w * v7;
            part = DPP_ADD(part, 0xB1);    // xor1
            part = DPP_ADD(part, 0x4E);    // xor2
            part = DPP_ADD(part, 0x141);   // half_mirror -> 8-lane (per-head) sum
            float p = live ? exp2f(part) : 0.f;
            l += p;
            c0 += p * x0; c1 += p * x1; c2 += p * x2; c3 += p * x3;
            c4 += p * x4; c5 += p * x5; c6 += p * x6; c7 += p * x7;
        };

        body(us, valid);                         // implicit self-loop
        for (int j = 0; j < nmax; j += 4) {
            int e = e0 + j;
            int q0 = col[e], q1 = col[e + 1], q2 = col[e + 2], q3 = col[e + 3];
            short8 r0 = *(const short8*)(xl + (size_t)q0 * 256 + s * 8);
            short8 r1 = *(const short8*)(xl + (size_t)q1 * 256 + s * 8);
            short8 r2 = *(const short8*)(xl + (size_t)q2 * 256 + s * 8);
            short8 r3 = *(const short8*)(xl + (size_t)q3 * 256 + s * 8);
            body(r0, j + 0 < nl);
            body(r1, j + 1 < nl);
            body(r2, j + 2 < nl);
            body(r3, j + 3 < nl);
        }

        float inv = __builtin_amdgcn_rcpf(l);    // l>0 for valid (self alive)
        float t0 = c0 * inv + bcL.x, t1 = c1 * inv + bcL.y;
        float t2 = c2 * inv + bcL.z, t3 = c3 * inv + bcL.w;
        float t4 = c4 * inv + bcH.x, t5 = c5 * inv + bcH.y;
        float t6 = c6 * inv + bcH.z, t7 = c7 * inv + bcH.w;
        // sum over 4 heads: lanes s, s^8, s^16, s^24 (within each half)
        t0 += __shfl_xor(t0, 8, 64); t0 += __shfl_xor(t0, 16, 64);
        t1 += __shfl_xor(t1, 8, 64); t1 += __shfl_xor(t1, 16, 64);
        t2 += __shfl_xor(t2, 8, 64); t2 += __shfl_xor(t2, 16, 64);
        t3 += __shfl_xor(t3, 8, 64); t3 += __shfl_xor(t3, 16, 64);
        t4 += __shfl_xor(t4, 8, 64); t4 += __shfl_xor(t4, 16, 64);
        t5 += __shfl_xor(t5, 8, 64); t5 += __shfl_xor(t5, 16, 64);
        t6 += __shfl_xor(t6, 8, 64); t6 += __shfl_xor(t6, 16, 64);
        t7 += __shfl_xor(t7, 8, 64); t7 += __shfl_xor(t7, 16, 64);
        if (valid && s < 8) {
            short8 o;
            o[0] = (short)f2b(tanhf(t0)); o[1] = (short)f2b(tanhf(t1));
            o[2] = (short)f2b(tanhf(t2)); o[3] = (short)f2b(tanhf(t3));
            o[4] = (short)f2b(tanhf(t4)); o[5] = (short)f2b(tanhf(t5));
            o[6] = (short)f2b(tanhf(t6)); o[7] = (short)f2b(tanhf(t7));
            *(short8*)(hp + (size_t)ridx * 128 + s * 8) = o;
        }
    }
}

// ---------------------------------------------------------------- out = (h @ Wg + bg) * (cs>0), idx-major (streams hp)
__global__ __launch_bounds__(256) void k_out(const bf16_t* __restrict__ hp,
                                             const bf16_t* __restrict__ h0,
                                             const int* __restrict__ order,
                                             const float* __restrict__ Wg,
                                             const float* __restrict__ bg,
                                             const int* __restrict__ cs,
                                             void* __restrict__ out,
                                             const int* __restrict__ flag,
                                             const int* __restrict__ mbuf) {
    __shared__ float Ws[HID * OUTD];
    __shared__ float bs[OUTD];
    int t = threadIdx.x;
    for (int i = t; i < HID * OUTD; i += 256) Ws[i] = Wg[i];
    if (t < OUTD) bs[t] = bg[t];
    __syncthreads();
    int g0 = t >> 5, c = t & 31;
    int fl = *flag;
    int c0cnt = mbuf[8];
#pragma unroll
    for (int g = 0; g < 4; g++) {
        int idx = blockIdx.x * 32 + g * 8 + g0;
        if (idx >= NN) break;
        int node = order[idx];
        float res = 0.f;
        if (cs[node] > 0) {
            const bf16_t* hr = (idx < c0cnt) ? (hp + (size_t)idx * 128)
                                             : (h0 + (size_t)node * HID);
            const short8* hr8 = (const short8*)hr;
            float acc = bs[c];
#pragma unroll
            for (int j = 0; j < 8; j++) {
                short8 hv = hr8[j];
#pragma unroll
                for (int k = 0; k < 8; k++)
                    acc += b2f((bf16_t)hv[k]) * Ws[(j * 8 + k) * OUTD + c];
            }
            res = acc;
        }
        size_t oidx = (size_t)node * OUTD + c;
        if (fl) ((bf16_t*)out)[oidx] = f2b(res);
        else    ((float*)out)[oidx]  = res;
    }
}

// ---------------------------------------------------------------- host
static inline size_t alignup(size_t x) { return (x + 255) & ~(size_t)255; }

extern "C" void kernel_launch(void* const* d_in, const int* in_sizes, int n_in,
                              void* d_out, int out_size, void* d_ws, size_t ws_size,
                              hipStream_t stream) {
    const void* feat_raw  = d_in[0];
    const void* W_in_raw  = d_in[1];
    const void* b_in_raw  = d_in[2];
    const void* Wl_raw    = d_in[3];
    const void* bl_raw    = d_in[4];
    const void* Wr_raw    = d_in[5];
    const void* br_raw    = d_in[6];
    const void* att_raw   = d_in[7];
    const void* bconv_raw = d_in[8];
    const void* Wg_raw    = d_in[9];
    const void* bg_raw    = d_in[10];
    const int* edge       = (const int*)d_in[11];    // [2][EE]: src row, dst row
    const int* nmask      = (const int*)d_in[12];
    const int* cstate     = (const int*)d_in[13];

    const int* e_src = edge;
    const int* e_dst = edge + EE;

    const size_t SZ_HB   = alignup((size_t)NN * HID * sizeof(bf16_t));
    const size_t SZ_HP   = alignup((size_t)NN * 128 * sizeof(bf16_t));
    const size_t SZ_X    = alignup((size_t)NN * 256 * sizeof(bf16_t));
    const size_t SZ_I4   = alignup((size_t)NN * 4 * sizeof(int));   // deg4/cur4/rend4/re_p
    const size_t SZ_I    = alignup((size_t)NN * sizeof(int));
    const size_t SZ_COL  = alignup((size_t)EE * sizeof(int));
    const int nch = (NN + 1023) / 1024;
    const size_t SZ_BC   = alignup((size_t)NBC * sizeof(int));
    const size_t SZ_WT   = alignup((size_t)512 * 128 * sizeof(bf16_t));
    const size_t SZ_WTS  = alignup((size_t)512 * 64 * sizeof(bf16_t));
    const size_t SZ_B    = alignup(512 * sizeof(float));
    const size_t SZ_WG   = alignup((size_t)HID * OUTD * sizeof(float));

    char* w = (char*)d_ws;
    bf16_t* h0   = (bf16_t*)w; w += SZ_HB;
    bf16_t* hp   = (bf16_t*)w; w += SZ_HP;
    bf16_t* xl   = (bf16_t*)w; w += SZ_X;
    bf16_t* xr   = (bf16_t*)w; w += SZ_X;
    int* deg4    = (int*)w;    w += SZ_I4;
    int* mbuf    = (int*)w;    w += 256;     // adjacent to deg4: one memset covers both
    int* cur4    = (int*)w;    w += SZ_I4;
    int* rend4   = (int*)w;    w += SZ_I4;
    int* re_p    = (int*)w;    w += SZ_I4;
    int* colA    = (int*)w;    w += SZ_COL;  // k_agg may over-read a little into order[]
    int* order   = (int*)w;    w += SZ_I;
    int* rank    = (int*)w;    w += SZ_I;
    int* bcount  = (int*)w;    w += SZ_BC;
    bf16_t* Wt   = (bf16_t*)w; w += SZ_WT;
    bf16_t* WtS  = (bf16_t*)w; w += SZ_WTS;
    float* bb    = (float*)w;  w += SZ_B;
    float* attf  = (float*)w;  w += SZ_B;
    float* bcf   = (float*)w;  w += SZ_B;
    float* Wgf   = (float*)w;  w += SZ_WG;
    float* bgf   = (float*)w;  w += SZ_B;
    int* flag    = (int*)w;    w += 256;
    if ((size_t)(w - (char*)d_ws) > ws_size) return;

    // ---- zero deg4 + mbuf in one async memset (they are adjacent)
    hipMemsetAsync(deg4, 0, SZ_I4 + 256, stream);

    // ---- fused setup: flag + weights + bucket counts + edge hist + h0
    k_setup<<<267 + NB_NODE + EB + H0_BLOCKS, 256, 0, stream>>>(
        W_in_raw, b_in_raw, att_raw, bconv_raw, Wg_raw, bg_raw,
        Wl_raw, Wr_raw, bl_raw, br_raw, feat_raw, nmask, e_src, e_dst,
        attf, bcf, Wgf, bgf, Wt, WtS, bb, deg4, flag, bcount, h0);

    // ---- CSR (bucket-sorted) + compaction (+rank, +re_p)
    k_scan<<<nch, 256, 0, stream>>>(deg4, cur4, rend4, bcount, mbuf, NN, nch);
    k_scatter_all<<<(EE + 255) / 256, 256, 0, stream>>>(e_src, e_dst, cur4, colA,
                                                        nmask, rend4, mbuf,
                                                        order, rank, re_p);
    // ---- pack into order space: col -> ranks, hp[idx] = [h0|h0]
    k_pack<<<PB_COL + PB_HP, 256, 0, stream>>>(colA, rank, order, h0, hp);

    // ---- step 0: K=64 gemm with pre-summed weights, then agg
    k_gemm0<<<dim3((NN + 63) / 64, 4), 256, 0, stream>>>(hp, WtS, bb, xl, xr, mbuf);
    k_agg<0><<<2048, 256, 0, stream>>>(hp, xl, xr, attf, bcf, re_p, colA, mbuf);

    // ---- steps 1,2: K=128 gemm + agg
    k_gemm_mfma<<<dim3((NN + 63) / 64, 4), 256, 0, stream>>>(hp, Wt, bb, xl, xr, mbuf, 1);
    k_agg<1><<<2048, 256, 0, stream>>>(hp, xl, xr, attf, bcf, re_p, colA, mbuf);
    k_gemm_mfma<<<dim3((NN + 63) / 64, 4), 256, 0, stream>>>(hp, Wt, bb, xl, xr, mbuf, 2);
    k_agg<2><<<2048, 256, 0, stream>>>(hp, xl, xr, attf, bcf, re_p, colA, mbuf);

    // ---- epilogue (idx-major, streams hp)
    k_out<<<(NN + 31) / 32, 256, 0, stream>>>(hp, h0, order, Wgf, bgf, cstate,
                                              d_out, flag, mbuf);
}